// Round 4
// baseline (251.516 us; speedup 1.0000x reference)
//
#include <hip/hip_runtime.h>
#include <stdint.h>

// Disable FMA contraction file-wide: we must replicate the reference's
// per-op f32 rounding (decode + IoU) to avoid NMS decision flips.
#pragma clang fp contract(off)

#define B_IMGS   4
#define NLVL     5
#define A_TOTAL  242991
#define NSEL     4741          // 1000*4 + 741
#define NBUCK    8192          // 13-bit buckets: sign+exp+4 mantissa (os>>19)
#define BSHIFT   19
#define CAND_CAP 2048
#define POST_NMS 1000
#define NBL      (B_IMGS * NLVL)
#define NMS_TH   0.7f
#define NEGV     (-1e10f)
#define W_IMGF   1216.0f
#define H_IMGF   800.0f
#define MIN_SZ   1e-3f
#define BBOX_CLIP 4.135166556742356f   // log(1000/16), rounded to f32 by compiler

// ---------- level helpers ----------
__device__ __forceinline__ int lvl_k(int l) { return (l == 4) ? 741 : 1000; }
__device__ __forceinline__ void lvl_span(int l, int& lstart, int& n) {
    switch (l) {
    case 0: lstart = 0;      n = 182400; break;
    case 1: lstart = 182400; n = 45600;  break;
    case 2: lstart = 228000; n = 11400;  break;
    case 3: lstart = 239400; n = 2850;   break;
    default:lstart = 242250; n = 741;    break;
    }
}

// ---------- order-preserving float<->uint ----------
__device__ __forceinline__ unsigned flipf(float f) {
    unsigned u = __float_as_uint(f);
    return u ^ (unsigned)(((int)u >> 31) | 0x80000000);
}
__device__ __forceinline__ float unflipf(unsigned os) {
    unsigned u = (os & 0x80000000u) ? (os ^ 0x80000000u) : ~os;
    return __uint_as_float(u);
}

// ---------- async global->LDS DMA (16B per lane, wave-uniform LDS base) ----------
__device__ __forceinline__ void async_cp16(const void* g, void* l) {
    __builtin_amdgcn_global_load_lds(
        (const __attribute__((address_space(1))) unsigned*)g,
        (__attribute__((address_space(3))) unsigned*)l,
        16, 0, 0);
}

// ---------- workspace layout (hist/cand/cnt now LDS-only; NOTHING pre-zeroed) ----------
static constexpr size_t OFF_BM5   = 0;                                       // u32[20]
static constexpr size_t OFF_SEL   = 128;
static constexpr size_t OFF_BOXR  = OFF_SEL  + (size_t)B_IMGS * NSEL * 8;
static constexpr size_t OFF_SCR   = OFF_BOXR + (size_t)B_IMGS * NSEL * 16;
static constexpr size_t OFF_BOXL  = OFF_SCR  + (size_t)B_IMGS * NSEL * 4;
static constexpr size_t OFF_VAL   = OFF_BOXL + (size_t)B_IMGS * NSEL * 16;
static constexpr size_t OFF_RMAP  = OFF_VAL  + (size_t)B_IMGS * NSEL * 4;
static constexpr size_t OFF_KEEP  = OFF_RMAP + (size_t)B_IMGS * NSEL * 4;
static constexpr size_t OFF_MASK  = (OFF_KEEP + (size_t)B_IMGS * NSEL * 4 + 15) & ~(size_t)15;
static constexpr size_t WS_NEED   = OFF_MASK + (size_t)NBL * 1024 * 16 * 8;  // ~3.9 MB

// ---------- K1: per-(b,level) top-k entirely in-block ----------
// One block per (b,level): LDS histogram over the whole level span,
// wave-parallel threshold scan (R3-verified logic), compact into LDS,
// bitonic sort (R2-verified loop), write sorted top-kl to sel.
// No global hist/cand/cnt -> no pre-zeroing -> no memset node.
__global__ __launch_bounds__(1024) void k_topk(const float* __restrict__ obj,
                                               unsigned long long* __restrict__ sel) {
    __shared__ unsigned lh[NBUCK];                 // 32 KB
    __shared__ unsigned long long sbf[CAND_CAP];   // 16 KB
    __shared__ unsigned part[256];
    __shared__ unsigned wsum[4];
    __shared__ unsigned fcnt[4];
    __shared__ unsigned s_cum, s_thr, lcnt;
    const int tid = threadIdx.x;                   // 1024
    const int bl = blockIdx.x;
    const int b = bl / NLVL, l = bl - (bl / NLVL) * NLVL;
    int lstart, n;
    lvl_span(l, lstart, n);
    const int kl = lvl_k(l);

    for (int i = tid; i < NBUCK; i += 1024) lh[i] = 0;
    if (tid == 0) { lcnt = 0; s_cum = 0; }
    __syncthreads();

    // pass 1: histogram
    const float* src = obj + (size_t)b * A_TOTAL + lstart;
    for (int i = tid; i < n; i += 1024)
        atomicAdd(&lh[flipf(src[i]) >> BSHIFT], 1u);
    __syncthreads();

    // chunk sums (rotated LDS read: conflict-free; integer sum order-exact)
    if (tid < 256) {
        unsigned s = 0;
        #pragma unroll
        for (int i = 0; i < 32; ++i) s += lh[tid * 32 + ((i + tid) & 31)];
        part[tid] = s;
    }
    __syncthreads();

    // Stage 1: suffix(t) = sum_{u>=t} part[u] for t = 255 - tid via inclusive
    // prefix scan of reversed part[] across waves 0..3 (R3-verified).
    const int lane = tid & 63, wv = tid >> 6;
    unsigned suffix = 0;
    if (tid < 256) {
        unsigned x = part[255 - tid];
        #pragma unroll
        for (int d = 1; d < 64; d <<= 1) {
            unsigned up = __shfl_up(x, d);
            if (lane >= d) x += up;
        }
        if (lane == 63) wsum[wv] = x;
        suffix = x;
    }
    __syncthreads();
    if (tid < 256) {
        unsigned add = 0;
        #pragma unroll
        for (int u = 0; u < 3; ++u) if (u < wv) add += wsum[u];
        suffix += add;                       // suffix(255 - tid)
        unsigned long long bm = __ballot(suffix >= (unsigned)kl);
        if (lane == 0) fcnt[wv] = (unsigned)__popcll(bm);
    }
    __syncthreads();
    const int chnk = (int)(fcnt[0] + fcnt[1] + fcnt[2] + fcnt[3]) - 1;
    if (tid < 256 && (255 - tid) == chnk + 1) s_cum = suffix;  // 0 if chnk==255
    __syncthreads();
    // Stage 2 (wave 0): largest bucket i in chunk with suffix-sum >= kl
    if (tid < 64) {
        unsigned y = (tid < 32) ? lh[chnk * 32 + (31 - tid)] : 0u;
        #pragma unroll
        for (int d = 1; d < 32; d <<= 1) {
            unsigned up = __shfl_up(y, d);
            if (tid >= d) y += up;
        }
        unsigned suf2 = s_cum + y;           // bucket i = 31 - tid (tid < 32)
        unsigned long long bm2 = __ballot((tid < 32) && (suf2 >= (unsigned)kl));
        if (tid == 0) {
            int istar = (int)__popcll(bm2) - 1;
            s_thr = (unsigned)(chnk * 32 + istar);
        }
    }
    __syncthreads();
    const unsigned T = s_thr;

    // pass 2: compact passing entries into LDS
    for (int i = tid; i < n; i += 1024) {
        unsigned os = flipf(src[i]);
        if ((os >> BSHIFT) >= T) {
            unsigned slot = atomicAdd(&lcnt, 1u);
            if (slot < CAND_CAP)
                sbf[slot] = (((unsigned long long)(~os)) << 32) | (unsigned)(lstart + i);
        }
    }
    __syncthreads();
    unsigned m = lcnt; if (m > CAND_CAP) m = CAND_CAP;
    for (int i = tid; i < CAND_CAP; i += 1024)
        if ((unsigned)i >= m) sbf[i] = ~0ULL;
    __syncthreads();

    // bitonic sort: 1024 threads = exactly one compare-swap per pass
    for (int k = 2; k <= CAND_CAP; k <<= 1) {
        for (int j = k >> 1; j > 0; j >>= 1) {
            int i = ((tid / j) * (j << 1)) + (tid % j);
            int p = i + j;
            bool up = ((i & k) == 0);
            unsigned long long a = sbf[i], c = sbf[p];
            if ((a > c) == up) { sbf[i] = c; sbf[p] = a; }
            __syncthreads();
        }
    }
    for (int q = tid; q < kl; q += 1024)
        sel[(size_t)b * NSEL + l * 1000 + q] = sbf[q];
}

// ---------- binary search in LDS: #elements < key ----------
__device__ __forceinline__ int lbound_lds(const unsigned long long* s, int len,
                                          unsigned long long key) {
    int lo = 0, hi = len;
    while (lo < hi) {
        int mid = (lo + hi) >> 1;
        if (s[mid] < key) lo = mid + 1; else hi = mid;
    }
    return lo;
}

// ---------- K2: decode+clip+valid; global rank via LDS 5-way merge-rank ----------
// grid (5, b) x 1024 threads. Per-block max -> private boxmax5 slot (plain
// store, no atomic, no pre-zeroed memory).
__global__ void k_decode(const float* __restrict__ deltas, const float* __restrict__ anchors,
                         const unsigned long long* __restrict__ sel,
                         float* __restrict__ boxes_r, float* __restrict__ score_r,
                         float* __restrict__ boxes_l, int* __restrict__ valid_l,
                         int* __restrict__ rankmap, unsigned* __restrict__ boxmax5) {
    __shared__ unsigned long long skey[NSEL];     // 37,928 B
    __shared__ float wmax[16];
    const int b = blockIdx.y;
    const int tid = threadIdx.x;                  // 1024
    for (int i = tid; i < NSEL; i += 1024)
        skey[i] = sel[(size_t)b * NSEL + i];
    __syncthreads();

    int p = blockIdx.x * 1024 + tid;
    bool on = p < NSEL;
    float mx = 0.0f;
    if (on) {
        int l = p / 1000;           // p in [4000,4741) -> 4
        int q = p - l * 1000;
        unsigned long long key = skey[p];
        unsigned a = (unsigned)(key & 0xFFFFFFFFu);
        unsigned os = ~((unsigned)(key >> 32));
        if (a >= A_TOTAL) a = 0;    // impossible-path safety (MAX padding)
        float score = unflipf(os);
        // global rank = q + sum over other levels of (#keys < key)
        int r = q;
        for (int l2 = 0; l2 < NLVL; ++l2) {
            if (l2 == l) continue;
            r += lbound_lds(skey + l2 * 1000, lvl_k(l2), key);
        }
        // decode (replicates reference op order; contraction disabled)
        const float* dv = deltas + ((size_t)b * A_TOTAL + a) * 4;
        const float* av = anchors + (size_t)a * 4;
        float ax1 = av[0], ay1 = av[1], ax2 = av[2], ay2 = av[3];
        float wa = ax2 - ax1, ha = ay2 - ay1;
        float cxa = ax1 + 0.5f * wa, cya = ay1 + 0.5f * ha;
        float dx = dv[0], dy = dv[1];
        float dw = fminf(dv[2], BBOX_CLIP), dh = fminf(dv[3], BBOX_CLIP);
        float cx = dx * wa + cxa, cy = dy * ha + cya;
        float w = expf(dw) * wa, h = expf(dh) * ha;
        float x1 = cx - 0.5f * w, y1 = cy - 0.5f * h;
        float x2 = cx + 0.5f * w, y2 = cy + 0.5f * h;
        float x1c = fminf(fmaxf(x1, 0.0f), W_IMGF);
        float y1c = fminf(fmaxf(y1, 0.0f), H_IMGF);
        float x2c = fminf(fmaxf(x2, 0.0f), W_IMGF);
        float y2c = fminf(fmaxf(y2, 0.0f), H_IMGF);
        int valid = ((x2c - x1c) >= MIN_SZ) && ((y2c - y1c) >= MIN_SZ);
        mx = fmaxf(fmaxf(x1c, y1c), fmaxf(x2c, y2c));
        size_t rp = (size_t)b * NSEL + r;
        boxes_r[rp * 4 + 0] = x1c; boxes_r[rp * 4 + 1] = y1c;
        boxes_r[rp * 4 + 2] = x2c; boxes_r[rp * 4 + 3] = y2c;
        score_r[rp] = score;
        size_t pp = (size_t)b * NSEL + p;
        boxes_l[pp * 4 + 0] = x1c; boxes_l[pp * 4 + 1] = y1c;
        boxes_l[pp * 4 + 2] = x2c; boxes_l[pp * 4 + 3] = y2c;
        valid_l[pp] = valid;
        rankmap[pp] = r;
    }
    // block max reduction -> private slot (coords >= 0; fmax is exact/orderless)
    #pragma unroll
    for (int o = 32; o > 0; o >>= 1)
        mx = fmaxf(mx, __shfl_xor(mx, o));
    if ((tid & 63) == 0) wmax[tid >> 6] = mx;
    __syncthreads();
    if (tid == 0) {
        float m2 = wmax[0];
        #pragma unroll
        for (int i = 1; i < 16; ++i) m2 = fmaxf(m2, wmax[i]);
        boxmax5[b * 5 + blockIdx.x] = __float_as_uint(m2);
    }
}

// ---------- K3: suppression bitmask (per (b,level), offset-box IoU) ----------
// mask layout: [bl][row (1024 stride)][16 u64 words]
// 256 threads/block; one 64-box column tile shared by 4 row-tiles.
__global__ void k_mask(const float* __restrict__ boxes_l, const unsigned* __restrict__ boxmax5,
                       unsigned long long* __restrict__ mask) {
    int bl = blockIdx.z;
    int b = bl / NLVL, l = bl - b * NLVL;
    int kl = lvl_k(l);
    int w = blockIdx.x, rg = blockIdx.y, tid = threadIdx.x;
    if (rg * 256 >= kl) return;              // whole block beyond level rows
    float M = __uint_as_float(boxmax5[b * 5 + 0]);
    #pragma unroll
    for (int j = 1; j < 5; ++j) M = fmaxf(M, __uint_as_float(boxmax5[b * 5 + j]));
    M += 1.0f;
    float off = (float)l * M;
    __shared__ float cb[64][5];
    int j0 = w * 64;
    if (tid < 64) {
        int j = j0 + tid;
        if (j < kl) {
            const float* bp = boxes_l + ((size_t)b * NSEL + l * 1000 + j) * 4;
            float x1 = bp[0] + off, y1 = bp[1] + off, x2 = bp[2] + off, y2 = bp[3] + off;
            cb[tid][0] = x1; cb[tid][1] = y1; cb[tid][2] = x2; cb[tid][3] = y2;
            cb[tid][4] = (x2 - x1) * (y2 - y1);
        }
    }
    __syncthreads();
    int i = rg * 256 + tid;
    if (i >= kl) return;
    unsigned long long word = 0;
    if (j0 + 63 > i) {
        const float* bp = boxes_l + ((size_t)b * NSEL + l * 1000 + i) * 4;
        float ix1 = bp[0] + off, iy1 = bp[1] + off, ix2 = bp[2] + off, iy2 = bp[3] + off;
        float ai = (ix2 - ix1) * (iy2 - iy1);
        int jmax = min(64, kl - j0);
        for (int bb = 0; bb < jmax; ++bb) {
            int jj = j0 + bb;
            if (jj <= i) continue;
            float ltx = fmaxf(ix1, cb[bb][0]), lty = fmaxf(iy1, cb[bb][1]);
            float rbx = fminf(ix2, cb[bb][2]), rby = fminf(iy2, cb[bb][3]);
            float ww = fmaxf(rbx - ltx, 0.0f), hh = fmaxf(rby - lty, 0.0f);
            float inter = ww * hh;
            float iou = inter / ((ai + cb[bb][4]) - inter);   // NaN>th == false, matches jnp
            if (iou > NMS_TH) word |= (1ULL << bb);
        }
    }
    mask[((size_t)bl * 1024 + i) * 16 + w] = word;
}

// ---------- K4: sequential greedy resolve (1 wave per (b,level)) ----------
// Serial loop visits ONLY rows with nonzero within-chunk diag word.
// Mask chunks DMA'd to LDS via global_load_lds, double-buffered.
__global__ void k_resolve(const int* __restrict__ valid_l, const int* __restrict__ rankmap,
                          const unsigned long long* __restrict__ mask, int* __restrict__ keep_r) {
    const int bl = blockIdx.x;
    const int b = bl / NLVL, l = bl - b * NLVL;
    const int kl = lvl_k(l);
    const int lane = threadIdx.x;     // 64 threads = 1 wave
    __shared__ __align__(16) unsigned long long sbufA[64 * 16];  // 8 KB, mirror layout
    __shared__ __align__(16) unsigned long long sbufB[64 * 16];  // 8 KB
    const int base = b * NSEL + l * 1000;

    // keep word per chunk, distributed: lane w (w<16) holds chunk w's keep bits
    unsigned long long keep_w = 0;
    for (int c = 0; c < 16; ++c) {
        int q = c * 64 + lane;
        int vv = (q < kl) ? valid_l[base + q] : 0;
        unsigned long long bm = __ballot(vv);
        if (lane == c) keep_w = bm;
    }

    const int nch = (kl + 63) >> 6;   // 16 or 12
    const char* mbyte = (const char*)(mask + (size_t)bl * 1024 * 16);

    // DMA chunk 0 -> sbufA (8 x 1KB instructions; lane scatters 16B each)
    {
        const char* g0 = mbyte + (size_t)lane * 16;
        #pragma unroll
        for (int j = 0; j < 8; ++j)
            async_cp16(g0 + j * 1024, (char*)sbufA + j * 1024);
    }

    for (int c = 0; c < nch; ++c) {
        unsigned long long* cur = (c & 1) ? sbufB : sbufA;
        unsigned long long* nxt = (c & 1) ? sbufA : sbufB;
        __syncthreads();                       // drains vmcnt: chunk c staged
        if (c + 1 < nch) {
            const char* g1 = mbyte + (size_t)(c + 1) * 8192 + (size_t)lane * 16;
            #pragma unroll
            for (int j = 0; j < 8; ++j)
                async_cp16(g1 + j * 1024, (char*)nxt + j * 1024);
        }
        unsigned long long kw = __shfl(keep_w, c);   // uniform
        if (kw) {
            // diagonal word (word c of this lane's row)
            unsigned long long diag = cur[lane * 16 + c];
            unsigned dlo = (unsigned)diag, dhi = (unsigned)(diag >> 32);
            // rows with zero diag suppress nothing in-chunk: skip them wholesale
            unsigned long long nz = __ballot(diag != 0ULL);
            unsigned long long rem = kw & nz;
            while (rem) {
                int r = __ffsll((long long)rem) - 1;
                unsigned lo = __builtin_amdgcn_readlane(dlo, r);
                unsigned hi = __builtin_amdgcn_readlane(dhi, r);
                unsigned long long d = ((unsigned long long)hi << 32) | lo;
                kw &= ~d;
                rem &= ~(d | (1ULL << r));
            }
            // batched cross-chunk suppression: lane w<16 ORs word w of kept rows
            unsigned long long supp = 0;
            if (lane < 16) {
                #pragma unroll
                for (int r = 0; r < 64; ++r) {
                    unsigned long long m = cur[r * 16 + lane];
                    supp |= (((kw >> r) & 1ULL) ? m : 0ULL);
                }
            }
            if (lane == c) keep_w = kw;
            else if (lane < 16 && lane > c) keep_w &= ~supp;
        }
    }
    __syncthreads();
    // scatter keep bits to global-rank order
    for (int c = 0; c < 16; ++c) {
        unsigned long long kwc = __shfl(keep_w, c);
        int q = c * 64 + lane;
        if (q < kl)
            keep_r[b * NSEL + rankmap[base + q]] = (int)((kwc >> lane) & 1ULL);
    }
}

// ---------- K5: compact kept entries (score order) into output ----------
// 1024 threads, CH=5 — short serial count/scatter tails per thread.
__global__ void k_output(const int* __restrict__ keep_r, const float* __restrict__ boxes_r,
                         const float* __restrict__ score_r, float* __restrict__ out) {
    int b = blockIdx.x, tid = threadIdx.x;    // 1024
    float* ob = out + (size_t)b * POST_NMS * 4;
    float* osc = out + (size_t)B_IMGS * POST_NMS * 4 + (size_t)b * POST_NMS;
    for (int p = tid; p < POST_NMS; p += 1024) {
        ob[p * 4 + 0] = 0.0f; ob[p * 4 + 1] = 0.0f;
        ob[p * 4 + 2] = 0.0f; ob[p * 4 + 3] = 0.0f;
        osc[p] = NEGV;
    }
    __syncthreads();   // global writes drained before barrier (vmcnt)
    const int CH = 5;  // 5*1024 = 5120 >= 4741
    int base = tid * CH;
    int cnt = 0;
    #pragma unroll
    for (int k = 0; k < CH; ++k) {
        int r = base + k;
        if (r < NSEL) cnt += keep_r[b * NSEL + r];
    }
    __shared__ int ps[1024];
    ps[tid] = cnt;
    __syncthreads();
    for (int ofs = 1; ofs < 1024; ofs <<= 1) {
        int v = (tid >= ofs) ? ps[tid - ofs] : 0;
        __syncthreads();
        ps[tid] += v;
        __syncthreads();
    }
    int p = ps[tid] - cnt;   // exclusive prefix
    #pragma unroll
    for (int k = 0; k < CH; ++k) {
        int r = base + k;
        if (r < NSEL && keep_r[b * NSEL + r]) {
            if (p < POST_NMS) {
                const float* bp = boxes_r + ((size_t)b * NSEL + r) * 4;
                ob[p * 4 + 0] = bp[0]; ob[p * 4 + 1] = bp[1];
                ob[p * 4 + 2] = bp[2]; ob[p * 4 + 3] = bp[3];
                osc[p] = score_r[(size_t)b * NSEL + r];
            }
            ++p;
        }
    }
}

extern "C" void kernel_launch(void* const* d_in, const int* in_sizes, int n_in,
                              void* d_out, int out_size, void* d_ws, size_t ws_size,
                              hipStream_t stream) {
    const float* obj     = (const float*)d_in[0];   // [4, 242991]
    const float* deltas  = (const float*)d_in[1];   // [4, 242991, 4]
    const float* anchors = (const float*)d_in[2];   // [242991, 4]
    float* out = (float*)d_out;                     // [4,1000,4] ++ [4,1000]

    char* ws = (char*)d_ws;
    unsigned*            boxmax5 = (unsigned*)(ws + OFF_BM5);
    unsigned long long*  sel     = (unsigned long long*)(ws + OFF_SEL);
    float*               boxes_r = (float*)(ws + OFF_BOXR);
    float*               score_r = (float*)(ws + OFF_SCR);
    float*               boxes_l = (float*)(ws + OFF_BOXL);
    int*                 valid_l = (int*)(ws + OFF_VAL);
    int*                 rankmap = (int*)(ws + OFF_RMAP);
    int*                 keep_r  = (int*)(ws + OFF_KEEP);
    unsigned long long*  maskp   = (unsigned long long*)(ws + OFF_MASK);

    (void)in_sizes; (void)n_in; (void)out_size; (void)ws_size; (void)WS_NEED;

    // No memset: every workspace word consumed is written first (boxmax5 by
    // plain stores; hist/cand/cnt live in LDS; rankmap is a permutation).
    k_topk<<<NBL, 1024, 0, stream>>>(obj, sel);
    k_decode<<<dim3(5, B_IMGS), 1024, 0, stream>>>(
        deltas, anchors, sel, boxes_r, score_r, boxes_l, valid_l, rankmap, boxmax5);
    k_mask<<<dim3(16, 4, NBL), 256, 0, stream>>>(boxes_l, boxmax5, maskp);
    k_resolve<<<NBL, 64, 0, stream>>>(valid_l, rankmap, maskp, keep_r);
    k_output<<<B_IMGS, 1024, 0, stream>>>(keep_r, boxes_r, score_r, out);
}

// Round 5
// 198.512 us; speedup vs baseline: 1.2670x; 1.2670x over previous
//
#include <hip/hip_runtime.h>
#include <stdint.h>

// Disable FMA contraction file-wide: we must replicate the reference's
// per-op f32 rounding (decode + IoU) to avoid NMS decision flips.
#pragma clang fp contract(off)

#define B_IMGS   4
#define NLVL     5
#define A_TOTAL  242991
#define NSEL     4741          // 1000*4 + 741
#define NBUCK    8192          // 13-bit buckets: sign+exp+4 mantissa (os>>19)
#define BSHIFT   19
#define CAND_CAP 2048
#define POST_NMS 1000
#define NBL      (B_IMGS * NLVL)
#define NMS_TH   0.7f
#define NEGV     (-1e10f)
#define W_IMGF   1216.0f
#define H_IMGF   800.0f
#define MIN_SZ   1e-3f
#define BBOX_CLIP 4.135166556742356f   // log(1000/16), rounded to f32 by compiler

// ---------- level helpers ----------
__device__ __forceinline__ int lvl_k(int l) { return (l == 4) ? 741 : 1000; }
__device__ __forceinline__ void lvl_span(int l, int& lstart, int& n) {
    switch (l) {
    case 0: lstart = 0;      n = 182400; break;
    case 1: lstart = 182400; n = 45600;  break;
    case 2: lstart = 228000; n = 11400;  break;
    case 3: lstart = 239400; n = 2850;   break;
    default:lstart = 242250; n = 741;    break;
    }
}

// ---------- order-preserving float<->uint ----------
__device__ __forceinline__ unsigned flipf(float f) {
    unsigned u = __float_as_uint(f);
    return u ^ (unsigned)(((int)u >> 31) | 0x80000000);
}
__device__ __forceinline__ float unflipf(unsigned os) {
    unsigned u = (os & 0x80000000u) ? (os ^ 0x80000000u) : ~os;
    return __uint_as_float(u);
}

// ---------- async global->LDS DMA (16B per lane, wave-uniform LDS base) ----------
__device__ __forceinline__ void async_cp16(const void* g, void* l) {
    __builtin_amdgcn_global_load_lds(
        (const __attribute__((address_space(1))) unsigned*)g,
        (__attribute__((address_space(3))) unsigned*)l,
        16, 0, 0);
}

// ---------- workspace layout (hist/cand/cnt LDS-only; NOTHING pre-zeroed) ----------
static constexpr size_t OFF_BM5   = 0;                                       // u32[20]
static constexpr size_t OFF_SEL   = 128;
static constexpr size_t OFF_BOXR  = OFF_SEL  + (size_t)B_IMGS * NSEL * 8;
static constexpr size_t OFF_SCR   = OFF_BOXR + (size_t)B_IMGS * NSEL * 16;
static constexpr size_t OFF_BOXL  = OFF_SCR  + (size_t)B_IMGS * NSEL * 4;
static constexpr size_t OFF_VAL   = OFF_BOXL + (size_t)B_IMGS * NSEL * 16;
static constexpr size_t OFF_RMAP  = OFF_VAL  + (size_t)B_IMGS * NSEL * 4;
static constexpr size_t OFF_KEEP  = OFF_RMAP + (size_t)B_IMGS * NSEL * 4;
static constexpr size_t OFF_MASK  = (OFF_KEEP + (size_t)B_IMGS * NSEL * 4 + 15) & ~(size_t)15;
static constexpr size_t WS_NEED   = OFF_MASK + (size_t)NBL * 1024 * 16 * 8;  // ~3.9 MB

// ---------- K1: per-(b,level) top-k entirely in-block ----------
// R4-verified logic; scan passes now float4-vectorized with deep manual
// unrolling (16 / 8 elements in flight per thread) to break the 1-outstanding-
// load latency chain that made R4's k_topk 138 us. Alignment peel handles the
// 4B-only base alignment (A_TOTAL odd). Levels with n <= k skip hist entirely.
__global__ __launch_bounds__(1024) void k_topk(const float* __restrict__ obj,
                                               unsigned long long* __restrict__ sel) {
    __shared__ unsigned lh[NBUCK];                 // 32 KB
    __shared__ unsigned long long sbf[CAND_CAP];   // 16 KB
    __shared__ unsigned part[256];
    __shared__ unsigned wsum[4];
    __shared__ unsigned fcnt[4];
    __shared__ unsigned s_cum, s_thr, lcnt;
    const int tid = threadIdx.x;                   // 1024
    const int bl = blockIdx.x;
    const int b = bl / NLVL, l = bl - (bl / NLVL) * NLVL;
    int lstart, n;
    lvl_span(l, lstart, n);
    const int kl = lvl_k(l);

    if (tid == 0) { lcnt = 0; s_cum = 0; }

    const float* src = obj + (size_t)b * A_TOTAL + lstart;
    const int peel0 = (int)(((16u - ((unsigned)(uintptr_t)src & 15u)) & 15u) >> 2);
    const int peel  = (peel0 < n) ? peel0 : n;     // 0..3 scalar floats to 16B
    const int nv    = (n - peel) >> 2;             // # aligned float4
    const float4* s4 = (const float4*)(src + peel);
    const int tail0 = peel + (nv << 2);

    unsigned T = 0;
    if (n > kl) {
        for (int i = tid; i < NBUCK; i += 1024) lh[i] = 0;
        __syncthreads();

        // ---- pass 1: histogram (float4, 4-deep unroll) ----
#define H1(f) atomicAdd(&lh[flipf(f) >> BSHIFT], 1u)
#define H4(v) do { H1((v).x); H1((v).y); H1((v).z); H1((v).w); } while (0)
        if (tid < peel) H1(src[tid]);
        for (int i = tid; i < nv; i += 4096) {
            if (i + 3072 < nv) {
                float4 a0 = s4[i], a1 = s4[i + 1024], a2 = s4[i + 2048], a3 = s4[i + 3072];
                H4(a0); H4(a1); H4(a2); H4(a3);
            } else {
                float4 a0 = s4[i]; H4(a0);
                if (i + 1024 < nv) { float4 a = s4[i + 1024]; H4(a); }
                if (i + 2048 < nv) { float4 a = s4[i + 2048]; H4(a); }
            }
        }
        for (int i = tail0 + tid; i < n; i += 1024) H1(src[i]);
#undef H4
#undef H1
        __syncthreads();

        // ---- chunk sums (rotated read: conflict-free; integer sum exact) ----
        if (tid < 256) {
            unsigned s = 0;
            #pragma unroll
            for (int i = 0; i < 32; ++i) s += lh[tid * 32 + ((i + tid) & 31)];
            part[tid] = s;
        }
        __syncthreads();

        // ---- Stage 1: suffix(t) via inclusive scan of reversed part[] ----
        const int lane = tid & 63, wv = tid >> 6;
        unsigned suffix = 0;
        if (tid < 256) {
            unsigned x = part[255 - tid];
            #pragma unroll
            for (int d = 1; d < 64; d <<= 1) {
                unsigned up = __shfl_up(x, d);
                if (lane >= d) x += up;
            }
            if (lane == 63) wsum[wv] = x;
            suffix = x;
        }
        __syncthreads();
        if (tid < 256) {
            unsigned add = 0;
            #pragma unroll
            for (int u = 0; u < 3; ++u) if (u < wv) add += wsum[u];
            suffix += add;                       // suffix(255 - tid)
            unsigned long long bm = __ballot(suffix >= (unsigned)kl);
            if (lane == 0) fcnt[wv] = (unsigned)__popcll(bm);
        }
        __syncthreads();
        const int chnk = (int)(fcnt[0] + fcnt[1] + fcnt[2] + fcnt[3]) - 1;
        if (tid < 256 && (255 - tid) == chnk + 1) s_cum = suffix;  // 0 if chnk==255
        __syncthreads();
        // ---- Stage 2 (wave 0): largest bucket in chunk with suffix >= kl ----
        if (tid < 64) {
            unsigned y = (tid < 32) ? lh[chnk * 32 + (31 - tid)] : 0u;
            #pragma unroll
            for (int d = 1; d < 32; d <<= 1) {
                unsigned up = __shfl_up(y, d);
                if (tid >= d) y += up;
            }
            unsigned suf2 = s_cum + y;           // bucket i = 31 - tid (tid < 32)
            unsigned long long bm2 = __ballot((tid < 32) && (suf2 >= (unsigned)kl));
            if (tid == 0) {
                int istar = (int)__popcll(bm2) - 1;
                s_thr = (unsigned)(chnk * 32 + istar);
            }
        }
        __syncthreads();
        T = s_thr;
    } else {
        __syncthreads();   // publish lcnt = 0 (n <= k: every element passes, T = 0)
    }

    // ---- pass 2: compact passing entries into LDS (float4, 2-deep unroll) ----
#define E1(f, idx) do { unsigned os_ = flipf(f); \
    if ((os_ >> BSHIFT) >= T) { \
        unsigned slot = atomicAdd(&lcnt, 1u); \
        if (slot < CAND_CAP) \
            sbf[slot] = (((unsigned long long)(~os_)) << 32) | (unsigned)(idx); \
    } } while (0)
#define E4(v, gb) do { E1((v).x, (gb)); E1((v).y, (gb) + 1); \
                       E1((v).z, (gb) + 2); E1((v).w, (gb) + 3); } while (0)
    if (tid < peel) E1(src[tid], lstart + tid);
    for (int i = tid; i < nv; i += 2048) {
        const int gb0 = lstart + peel + (i << 2);
        if (i + 1024 < nv) {
            float4 a0 = s4[i], a1 = s4[i + 1024];
            E4(a0, gb0);
            E4(a1, gb0 + 4096);
        } else {
            float4 a0 = s4[i];
            E4(a0, gb0);
        }
    }
    for (int i = tail0 + tid; i < n; i += 1024) E1(src[i], lstart + i);
#undef E4
#undef E1
    __syncthreads();
    unsigned m = lcnt; if (m > CAND_CAP) m = CAND_CAP;
    for (int i = tid; i < CAND_CAP; i += 1024)
        if ((unsigned)i >= m) sbf[i] = ~0ULL;
    __syncthreads();

    // bitonic sort: 1024 threads = exactly one compare-swap per pass
    for (int k = 2; k <= CAND_CAP; k <<= 1) {
        for (int j = k >> 1; j > 0; j >>= 1) {
            int i = ((tid / j) * (j << 1)) + (tid % j);
            int p = i + j;
            bool up = ((i & k) == 0);
            unsigned long long a = sbf[i], c = sbf[p];
            if ((a > c) == up) { sbf[i] = c; sbf[p] = a; }
            __syncthreads();
        }
    }
    for (int q = tid; q < kl; q += 1024)
        sel[(size_t)b * NSEL + l * 1000 + q] = sbf[q];
}

// ---------- binary search in LDS: #elements < key ----------
__device__ __forceinline__ int lbound_lds(const unsigned long long* s, int len,
                                          unsigned long long key) {
    int lo = 0, hi = len;
    while (lo < hi) {
        int mid = (lo + hi) >> 1;
        if (s[mid] < key) lo = mid + 1; else hi = mid;
    }
    return lo;
}

// ---------- K2: decode+clip+valid; global rank via LDS 5-way merge-rank ----------
// grid (5, b) x 1024 threads. Per-block max -> private boxmax5 slot (plain
// store, no atomic, no pre-zeroed memory).
__global__ void k_decode(const float* __restrict__ deltas, const float* __restrict__ anchors,
                         const unsigned long long* __restrict__ sel,
                         float* __restrict__ boxes_r, float* __restrict__ score_r,
                         float* __restrict__ boxes_l, int* __restrict__ valid_l,
                         int* __restrict__ rankmap, unsigned* __restrict__ boxmax5) {
    __shared__ unsigned long long skey[NSEL];     // 37,928 B
    __shared__ float wmax[16];
    const int b = blockIdx.y;
    const int tid = threadIdx.x;                  // 1024
    for (int i = tid; i < NSEL; i += 1024)
        skey[i] = sel[(size_t)b * NSEL + i];
    __syncthreads();

    int p = blockIdx.x * 1024 + tid;
    bool on = p < NSEL;
    float mx = 0.0f;
    if (on) {
        int l = p / 1000;           // p in [4000,4741) -> 4
        int q = p - l * 1000;
        unsigned long long key = skey[p];
        unsigned a = (unsigned)(key & 0xFFFFFFFFu);
        unsigned os = ~((unsigned)(key >> 32));
        if (a >= A_TOTAL) a = 0;    // impossible-path safety (MAX padding)
        float score = unflipf(os);
        // global rank = q + sum over other levels of (#keys < key)
        int r = q;
        for (int l2 = 0; l2 < NLVL; ++l2) {
            if (l2 == l) continue;
            r += lbound_lds(skey + l2 * 1000, lvl_k(l2), key);
        }
        // decode (replicates reference op order; contraction disabled)
        const float* dv = deltas + ((size_t)b * A_TOTAL + a) * 4;
        const float* av = anchors + (size_t)a * 4;
        float ax1 = av[0], ay1 = av[1], ax2 = av[2], ay2 = av[3];
        float wa = ax2 - ax1, ha = ay2 - ay1;
        float cxa = ax1 + 0.5f * wa, cya = ay1 + 0.5f * ha;
        float dx = dv[0], dy = dv[1];
        float dw = fminf(dv[2], BBOX_CLIP), dh = fminf(dv[3], BBOX_CLIP);
        float cx = dx * wa + cxa, cy = dy * ha + cya;
        float w = expf(dw) * wa, h = expf(dh) * ha;
        float x1 = cx - 0.5f * w, y1 = cy - 0.5f * h;
        float x2 = cx + 0.5f * w, y2 = cy + 0.5f * h;
        float x1c = fminf(fmaxf(x1, 0.0f), W_IMGF);
        float y1c = fminf(fmaxf(y1, 0.0f), H_IMGF);
        float x2c = fminf(fmaxf(x2, 0.0f), W_IMGF);
        float y2c = fminf(fmaxf(y2, 0.0f), H_IMGF);
        int valid = ((x2c - x1c) >= MIN_SZ) && ((y2c - y1c) >= MIN_SZ);
        mx = fmaxf(fmaxf(x1c, y1c), fmaxf(x2c, y2c));
        size_t rp = (size_t)b * NSEL + r;
        boxes_r[rp * 4 + 0] = x1c; boxes_r[rp * 4 + 1] = y1c;
        boxes_r[rp * 4 + 2] = x2c; boxes_r[rp * 4 + 3] = y2c;
        score_r[rp] = score;
        size_t pp = (size_t)b * NSEL + p;
        boxes_l[pp * 4 + 0] = x1c; boxes_l[pp * 4 + 1] = y1c;
        boxes_l[pp * 4 + 2] = x2c; boxes_l[pp * 4 + 3] = y2c;
        valid_l[pp] = valid;
        rankmap[pp] = r;
    }
    // block max reduction -> private slot (coords >= 0; fmax is exact/orderless)
    #pragma unroll
    for (int o = 32; o > 0; o >>= 1)
        mx = fmaxf(mx, __shfl_xor(mx, o));
    if ((tid & 63) == 0) wmax[tid >> 6] = mx;
    __syncthreads();
    if (tid == 0) {
        float m2 = wmax[0];
        #pragma unroll
        for (int i = 1; i < 16; ++i) m2 = fmaxf(m2, wmax[i]);
        boxmax5[b * 5 + blockIdx.x] = __float_as_uint(m2);
    }
}

// ---------- K3: suppression bitmask (per (b,level), offset-box IoU) ----------
// mask layout: [bl][row (1024 stride)][16 u64 words]
// 256 threads/block; one 64-box column tile shared by 4 row-tiles.
__global__ void k_mask(const float* __restrict__ boxes_l, const unsigned* __restrict__ boxmax5,
                       unsigned long long* __restrict__ mask) {
    int bl = blockIdx.z;
    int b = bl / NLVL, l = bl - b * NLVL;
    int kl = lvl_k(l);
    int w = blockIdx.x, rg = blockIdx.y, tid = threadIdx.x;
    if (rg * 256 >= kl) return;              // whole block beyond level rows
    float M = __uint_as_float(boxmax5[b * 5 + 0]);
    #pragma unroll
    for (int j = 1; j < 5; ++j) M = fmaxf(M, __uint_as_float(boxmax5[b * 5 + j]));
    M += 1.0f;
    float off = (float)l * M;
    __shared__ float cb[64][5];
    int j0 = w * 64;
    if (tid < 64) {
        int j = j0 + tid;
        if (j < kl) {
            const float* bp = boxes_l + ((size_t)b * NSEL + l * 1000 + j) * 4;
            float x1 = bp[0] + off, y1 = bp[1] + off, x2 = bp[2] + off, y2 = bp[3] + off;
            cb[tid][0] = x1; cb[tid][1] = y1; cb[tid][2] = x2; cb[tid][3] = y2;
            cb[tid][4] = (x2 - x1) * (y2 - y1);
        }
    }
    __syncthreads();
    int i = rg * 256 + tid;
    if (i >= kl) return;
    unsigned long long word = 0;
    if (j0 + 63 > i) {
        const float* bp = boxes_l + ((size_t)b * NSEL + l * 1000 + i) * 4;
        float ix1 = bp[0] + off, iy1 = bp[1] + off, ix2 = bp[2] + off, iy2 = bp[3] + off;
        float ai = (ix2 - ix1) * (iy2 - iy1);
        int jmax = min(64, kl - j0);
        for (int bb = 0; bb < jmax; ++bb) {
            int jj = j0 + bb;
            if (jj <= i) continue;
            float ltx = fmaxf(ix1, cb[bb][0]), lty = fmaxf(iy1, cb[bb][1]);
            float rbx = fminf(ix2, cb[bb][2]), rby = fminf(iy2, cb[bb][3]);
            float ww = fmaxf(rbx - ltx, 0.0f), hh = fmaxf(rby - lty, 0.0f);
            float inter = ww * hh;
            float iou = inter / ((ai + cb[bb][4]) - inter);   // NaN>th == false, matches jnp
            if (iou > NMS_TH) word |= (1ULL << bb);
        }
    }
    mask[((size_t)bl * 1024 + i) * 16 + w] = word;
}

// ---------- K4: sequential greedy resolve (1 wave per (b,level)) ----------
// Serial loop visits ONLY rows with nonzero within-chunk diag word.
// Mask chunks DMA'd to LDS via global_load_lds, double-buffered.
__global__ void k_resolve(const int* __restrict__ valid_l, const int* __restrict__ rankmap,
                          const unsigned long long* __restrict__ mask, int* __restrict__ keep_r) {
    const int bl = blockIdx.x;
    const int b = bl / NLVL, l = bl - b * NLVL;
    const int kl = lvl_k(l);
    const int lane = threadIdx.x;     // 64 threads = 1 wave
    __shared__ __align__(16) unsigned long long sbufA[64 * 16];  // 8 KB, mirror layout
    __shared__ __align__(16) unsigned long long sbufB[64 * 16];  // 8 KB
    const int base = b * NSEL + l * 1000;

    // keep word per chunk, distributed: lane w (w<16) holds chunk w's keep bits
    unsigned long long keep_w = 0;
    for (int c = 0; c < 16; ++c) {
        int q = c * 64 + lane;
        int vv = (q < kl) ? valid_l[base + q] : 0;
        unsigned long long bm = __ballot(vv);
        if (lane == c) keep_w = bm;
    }

    const int nch = (kl + 63) >> 6;   // 16 or 12
    const char* mbyte = (const char*)(mask + (size_t)bl * 1024 * 16);

    // DMA chunk 0 -> sbufA (8 x 1KB instructions; lane scatters 16B each)
    {
        const char* g0 = mbyte + (size_t)lane * 16;
        #pragma unroll
        for (int j = 0; j < 8; ++j)
            async_cp16(g0 + j * 1024, (char*)sbufA + j * 1024);
    }

    for (int c = 0; c < nch; ++c) {
        unsigned long long* cur = (c & 1) ? sbufB : sbufA;
        unsigned long long* nxt = (c & 1) ? sbufA : sbufB;
        __syncthreads();                       // drains vmcnt: chunk c staged
        if (c + 1 < nch) {
            const char* g1 = mbyte + (size_t)(c + 1) * 8192 + (size_t)lane * 16;
            #pragma unroll
            for (int j = 0; j < 8; ++j)
                async_cp16(g1 + j * 1024, (char*)nxt + j * 1024);
        }
        unsigned long long kw = __shfl(keep_w, c);   // uniform
        if (kw) {
            // diagonal word (word c of this lane's row)
            unsigned long long diag = cur[lane * 16 + c];
            unsigned dlo = (unsigned)diag, dhi = (unsigned)(diag >> 32);
            // rows with zero diag suppress nothing in-chunk: skip them wholesale
            unsigned long long nz = __ballot(diag != 0ULL);
            unsigned long long rem = kw & nz;
            while (rem) {
                int r = __ffsll((long long)rem) - 1;
                unsigned lo = __builtin_amdgcn_readlane(dlo, r);
                unsigned hi = __builtin_amdgcn_readlane(dhi, r);
                unsigned long long d = ((unsigned long long)hi << 32) | lo;
                kw &= ~d;
                rem &= ~(d | (1ULL << r));
            }
            // batched cross-chunk suppression: lane w<16 ORs word w of kept rows
            unsigned long long supp = 0;
            if (lane < 16) {
                #pragma unroll
                for (int r = 0; r < 64; ++r) {
                    unsigned long long m = cur[r * 16 + lane];
                    supp |= (((kw >> r) & 1ULL) ? m : 0ULL);
                }
            }
            if (lane == c) keep_w = kw;
            else if (lane < 16 && lane > c) keep_w &= ~supp;
        }
    }
    __syncthreads();
    // scatter keep bits to global-rank order
    for (int c = 0; c < 16; ++c) {
        unsigned long long kwc = __shfl(keep_w, c);
        int q = c * 64 + lane;
        if (q < kl)
            keep_r[b * NSEL + rankmap[base + q]] = (int)((kwc >> lane) & 1ULL);
    }
}

// ---------- K5: compact kept entries (score order) into output ----------
// 1024 threads, CH=5 — short serial count/scatter tails per thread.
__global__ void k_output(const int* __restrict__ keep_r, const float* __restrict__ boxes_r,
                         const float* __restrict__ score_r, float* __restrict__ out) {
    int b = blockIdx.x, tid = threadIdx.x;    // 1024
    float* ob = out + (size_t)b * POST_NMS * 4;
    float* osc = out + (size_t)B_IMGS * POST_NMS * 4 + (size_t)b * POST_NMS;
    for (int p = tid; p < POST_NMS; p += 1024) {
        ob[p * 4 + 0] = 0.0f; ob[p * 4 + 1] = 0.0f;
        ob[p * 4 + 2] = 0.0f; ob[p * 4 + 3] = 0.0f;
        osc[p] = NEGV;
    }
    __syncthreads();   // global writes drained before barrier (vmcnt)
    const int CH = 5;  // 5*1024 = 5120 >= 4741
    int base = tid * CH;
    int cnt = 0;
    #pragma unroll
    for (int k = 0; k < CH; ++k) {
        int r = base + k;
        if (r < NSEL) cnt += keep_r[b * NSEL + r];
    }
    __shared__ int ps[1024];
    ps[tid] = cnt;
    __syncthreads();
    for (int ofs = 1; ofs < 1024; ofs <<= 1) {
        int v = (tid >= ofs) ? ps[tid - ofs] : 0;
        __syncthreads();
        ps[tid] += v;
        __syncthreads();
    }
    int p = ps[tid] - cnt;   // exclusive prefix
    #pragma unroll
    for (int k = 0; k < CH; ++k) {
        int r = base + k;
        if (r < NSEL && keep_r[b * NSEL + r]) {
            if (p < POST_NMS) {
                const float* bp = boxes_r + ((size_t)b * NSEL + r) * 4;
                ob[p * 4 + 0] = bp[0]; ob[p * 4 + 1] = bp[1];
                ob[p * 4 + 2] = bp[2]; ob[p * 4 + 3] = bp[3];
                osc[p] = score_r[(size_t)b * NSEL + r];
            }
            ++p;
        }
    }
}

extern "C" void kernel_launch(void* const* d_in, const int* in_sizes, int n_in,
                              void* d_out, int out_size, void* d_ws, size_t ws_size,
                              hipStream_t stream) {
    const float* obj     = (const float*)d_in[0];   // [4, 242991]
    const float* deltas  = (const float*)d_in[1];   // [4, 242991, 4]
    const float* anchors = (const float*)d_in[2];   // [242991, 4]
    float* out = (float*)d_out;                     // [4,1000,4] ++ [4,1000]

    char* ws = (char*)d_ws;
    unsigned*            boxmax5 = (unsigned*)(ws + OFF_BM5);
    unsigned long long*  sel     = (unsigned long long*)(ws + OFF_SEL);
    float*               boxes_r = (float*)(ws + OFF_BOXR);
    float*               score_r = (float*)(ws + OFF_SCR);
    float*               boxes_l = (float*)(ws + OFF_BOXL);
    int*                 valid_l = (int*)(ws + OFF_VAL);
    int*                 rankmap = (int*)(ws + OFF_RMAP);
    int*                 keep_r  = (int*)(ws + OFF_KEEP);
    unsigned long long*  maskp   = (unsigned long long*)(ws + OFF_MASK);

    (void)in_sizes; (void)n_in; (void)out_size; (void)ws_size; (void)WS_NEED;

    // No memset: every workspace word consumed is written first (boxmax5 by
    // plain stores; hist/cand/cnt live in LDS; rankmap is a permutation).
    k_topk<<<NBL, 1024, 0, stream>>>(obj, sel);
    k_decode<<<dim3(5, B_IMGS), 1024, 0, stream>>>(
        deltas, anchors, sel, boxes_r, score_r, boxes_l, valid_l, rankmap, boxmax5);
    k_mask<<<dim3(16, 4, NBL), 256, 0, stream>>>(boxes_l, boxmax5, maskp);
    k_resolve<<<NBL, 64, 0, stream>>>(valid_l, rankmap, maskp, keep_r);
    k_output<<<B_IMGS, 1024, 0, stream>>>(keep_r, boxes_r, score_r, out);
}

// Round 6
// 184.943 us; speedup vs baseline: 1.3600x; 1.0734x over previous
//
#include <hip/hip_runtime.h>
#include <stdint.h>

// Disable FMA contraction file-wide: we must replicate the reference's
// per-op f32 rounding (decode + IoU) to avoid NMS decision flips.
#pragma clang fp contract(off)

#define B_IMGS   4
#define NLVL     5
#define A_TOTAL  242991
#define NSEL     4741          // 1000*4 + 741
#define NBUCK    8192          // 13-bit buckets: sign+exp+4 mantissa (os>>19)
#define BSHIFT   19
#define CAND_CAP 2048
#define POST_NMS 1000
#define NBL      (B_IMGS * NLVL)
#define NMS_TH   0.7f
#define NEGV     (-1e10f)
#define W_IMGF   1216.0f
#define H_IMGF   800.0f
#define MIN_SZ   1e-3f
#define BBOX_CLIP 4.135166556742356f   // log(1000/16), rounded to f32 by compiler

#define NSLICE_PER_IMG 34      // hist slices per image (l0:24 l1:6 l2:2 l3:1 l4:1-unused)

// ---------- level helpers ----------
__device__ __forceinline__ int lvl_k(int l) { return (l == 4) ? 741 : 1000; }

// ---------- order-preserving float<->uint ----------
__device__ __forceinline__ unsigned flipf(float f) {
    unsigned u = __float_as_uint(f);
    return u ^ (unsigned)(((int)u >> 31) | 0x80000000);
}
__device__ __forceinline__ float unflipf(unsigned os) {
    unsigned u = (os & 0x80000000u) ? (os ^ 0x80000000u) : ~os;
    return __uint_as_float(u);
}

// ---------- workspace layout (NOTHING pre-zeroed; cnt zeroed by k_hist) ----------
static constexpr size_t OFF_BM5   = 0;                                        // u32[20]
static constexpr size_t OFF_CNT   = 128;                                      // u32[20]
static constexpr size_t OFF_HSL   = 256;                                      // u32[4*34*8192]
static constexpr size_t OFF_PSL   = OFF_HSL  + (size_t)B_IMGS * NSLICE_PER_IMG * NBUCK * 4;
static constexpr size_t OFF_CAND  = OFF_PSL  + (size_t)B_IMGS * NSLICE_PER_IMG * 256 * 4;
static constexpr size_t OFF_SEL   = OFF_CAND + (size_t)NBL * CAND_CAP * 8;
static constexpr size_t OFF_BOXR  = OFF_SEL  + (size_t)B_IMGS * NSEL * 8;
static constexpr size_t OFF_SCR   = OFF_BOXR + (size_t)B_IMGS * NSEL * 16;
static constexpr size_t OFF_BOXL  = OFF_SCR  + (size_t)B_IMGS * NSEL * 4;
static constexpr size_t OFF_VAL   = OFF_BOXL + (size_t)B_IMGS * NSEL * 16;
static constexpr size_t OFF_RMAP  = OFF_VAL  + (size_t)B_IMGS * NSEL * 4;
static constexpr size_t OFF_MASK  = (OFF_RMAP + (size_t)B_IMGS * NSEL * 4 + 15) & ~(size_t)15;
static constexpr size_t WS_NEED   = OFF_MASK + (size_t)NBL * 1024 * 16 * 8;   // ~8.5 MB

// ---------- K1: per-span LDS histogram -> private global slice (no atomics) ----------
// 34 blocks/image, 512 threads. Slice s of image b at hist_sl[(b*34+s)*8192];
// per-slice chunk sums at part_sl[(b*34+s)*256]. l4 block zeroes cnt instead
// (n<=k: compact uses T=0, no hist needed).
#define HBLK_PER_IMG 34
__global__ __launch_bounds__(512) void k_hist(const float* __restrict__ obj,
                                              unsigned* __restrict__ hist_sl,
                                              unsigned* __restrict__ part_sl,
                                              unsigned* __restrict__ cnt) {
    __shared__ __align__(16) unsigned lh[NBUCK];   // 32 KB
    const int tid = threadIdx.x;     // 512
    const int b = blockIdx.x / HBLK_PER_IMG;
    const int r = blockIdx.x - b * HBLK_PER_IMG;
    if (r == 33) {                   // l4 block: just zero cnt once (b==0)
        if (b == 0 && tid < NBL) cnt[tid] = 0;
        return;
    }
    int sofs, sub, chunk, lstart, n;
    if (r < 24)      { sofs = 0;  sub = r;      chunk = 7600; lstart = 0;      n = 182400; }
    else if (r < 30) { sofs = 24; sub = r - 24; chunk = 7600; lstart = 182400; n = 45600; }
    else if (r < 32) { sofs = 30; sub = r - 30; chunk = 5700; lstart = 228000; n = 11400; }
    else             { sofs = 32; sub = 0;      chunk = 2850; lstart = 239400; n = 2850; }
    #pragma unroll
    for (int i = tid; i < NBUCK; i += 512) lh[i] = 0;
    __syncthreads();
    const int s0 = sub * chunk;
    const int m = min(chunk, n - s0);
    const float* src = obj + (size_t)b * A_TOTAL + lstart + s0;
    // vectorized histogram (float4 + 4-deep unroll; peel to 16B alignment)
    const int peel0 = (int)(((16u - ((unsigned)(uintptr_t)src & 15u)) & 15u) >> 2);
    const int peel  = (peel0 < m) ? peel0 : m;
    const int nv    = (m - peel) >> 2;
    const float4* s4 = (const float4*)(src + peel);
    const int tail0 = peel + (nv << 2);
#define H1(f) atomicAdd(&lh[flipf(f) >> BSHIFT], 1u)
#define H4(v) do { H1((v).x); H1((v).y); H1((v).z); H1((v).w); } while (0)
    if (tid < peel) H1(src[tid]);
    for (int i = tid; i < nv; i += 2048) {
        if (i + 1536 < nv) {
            float4 a0 = s4[i], a1 = s4[i + 512], a2 = s4[i + 1024], a3 = s4[i + 1536];
            H4(a0); H4(a1); H4(a2); H4(a3);
        } else {
            float4 a0 = s4[i]; H4(a0);
            if (i + 512  < nv) { float4 a = s4[i + 512];  H4(a); }
            if (i + 1024 < nv) { float4 a = s4[i + 1024]; H4(a); }
        }
    }
    for (int i = tail0 + tid; i < m; i += 512) H1(src[i]);
#undef H4
#undef H1
    __syncthreads();
    const int slice = b * NSLICE_PER_IMG + sofs + sub;
    unsigned* gh = hist_sl + (size_t)slice * NBUCK;
    #pragma unroll
    for (int i = tid; i < NBUCK / 4; i += 512)
        ((uint4*)gh)[i] = ((const uint4*)lh)[i];
    if (tid < 256) {
        unsigned s = 0;
        #pragma unroll
        for (int i = 0; i < 32; ++i) s += lh[tid * 32 + ((i + tid) & 31)];
        part_sl[(size_t)slice * 256 + tid] = s;
    }
}

// ---------- K2: threshold (from slice sums) + vectorized compact ----------
// 65 blocks/image, 256 threads. Threshold logic identical to R3-verified
// wave scan; inputs are integer sums over this bl's slices (deterministic,
// identical in every block of the bl).
#define CBLK_PER_IMG 65
__global__ __launch_bounds__(256) void k_compact(const float* __restrict__ obj,
                                                 const unsigned* __restrict__ hist_sl,
                                                 const unsigned* __restrict__ part_sl,
                                                 unsigned* __restrict__ cnt,
                                                 unsigned long long* __restrict__ cand) {
    __shared__ unsigned long long sbuf[CAND_CAP];   // 16 KB staging
    __shared__ unsigned wsum[4];
    __shared__ unsigned fcnt[4];
    __shared__ unsigned s_cum, s_thr, lcnt, gbase;
    const int tid = threadIdx.x;     // 256
    const int b = blockIdx.x / CBLK_PER_IMG;
    const int r = blockIdx.x - b * CBLK_PER_IMG;
    int l, sofs, nsub, sub, chunk, lstart, n;
    if (r < 48)      { l = 0; sofs = 0;  nsub = 24; sub = r;      chunk = 3800; lstart = 0;      n = 182400; }
    else if (r < 60) { l = 1; sofs = 24; nsub = 6;  sub = r - 48; chunk = 3800; lstart = 182400; n = 45600; }
    else if (r < 63) { l = 2; sofs = 30; nsub = 2;  sub = r - 60; chunk = 3800; lstart = 228000; n = 11400; }
    else if (r == 63){ l = 3; sofs = 32; nsub = 1;  sub = 0;      chunk = 2850; lstart = 239400; n = 2850; }
    else             { l = 4; sofs = 33; nsub = 0;  sub = 0;      chunk = 741;  lstart = 242250; n = 741; }
    const int bl = b * NLVL + l;
    const int kl = lvl_k(l);
    if (tid == 0) { lcnt = 0; s_cum = 0; }
    __syncthreads();
    unsigned T = 0;
    if (l < 4) {   // l4: n <= k -> every element passes, T = 0
        const int lane = tid & 63, wv = tid >> 6;
        // stage 1: suffix(t) over 256 chunk-sums (t = 255 - tid)
        const unsigned* pb = part_sl + (size_t)(b * NSLICE_PER_IMG + sofs) * 256 + (255 - tid);
        unsigned x = 0;
        #pragma unroll 6
        for (int s = 0; s < nsub; ++s) x += pb[(size_t)s * 256];
        #pragma unroll
        for (int d = 1; d < 64; d <<= 1) {
            unsigned up = __shfl_up(x, d);
            if (lane >= d) x += up;
        }
        if (lane == 63) wsum[wv] = x;
        __syncthreads();
        unsigned add = 0;
        #pragma unroll
        for (int u = 0; u < 3; ++u) if (u < wv) add += wsum[u];
        const unsigned suffix = x + add;                 // suffix(255 - tid)
        unsigned long long bm = __ballot(suffix >= (unsigned)kl);
        if (lane == 0) fcnt[wv] = (unsigned)__popcll(bm);
        __syncthreads();
        const int chnk = (int)(fcnt[0] + fcnt[1] + fcnt[2] + fcnt[3]) - 1;
        if ((255 - tid) == chnk + 1) s_cum = suffix;     // 0 if chnk==255
        __syncthreads();
        // stage 2 (wave 0): largest bucket in chunk with suffix >= kl
        if (tid < 64) {
            unsigned y = 0;
            if (tid < 32) {
                const unsigned* hb = hist_sl + (size_t)(b * NSLICE_PER_IMG + sofs) * NBUCK
                                   + chnk * 32 + (31 - tid);
                #pragma unroll 6
                for (int s = 0; s < nsub; ++s) y += hb[(size_t)s * NBUCK];
            }
            #pragma unroll
            for (int d = 1; d < 32; d <<= 1) {
                unsigned up = __shfl_up(y, d);
                if (tid >= d) y += up;
            }
            unsigned suf2 = s_cum + y;                   // bucket i = 31 - tid
            unsigned long long bm2 = __ballot((tid < 32) && (suf2 >= (unsigned)kl));
            if (tid == 0) {
                int istar = (int)__popcll(bm2) - 1;
                s_thr = (unsigned)(chnk * 32 + istar);
            }
        }
        __syncthreads();
        T = s_thr;
    }
    // ---- vectorized pass filter into LDS staging ----
    const int s0 = sub * chunk;
    const int m = min(chunk, n - s0);
    const int abase = lstart + s0;
    const float* src = obj + (size_t)b * A_TOTAL + abase;
    const int peel0 = (int)(((16u - ((unsigned)(uintptr_t)src & 15u)) & 15u) >> 2);
    const int peel  = (peel0 < m) ? peel0 : m;
    const int nv    = (m - peel) >> 2;
    const float4* s4 = (const float4*)(src + peel);
    const int tail0 = peel + (nv << 2);
#define E1(f, idx) do { unsigned os_ = flipf(f); \
    if ((os_ >> BSHIFT) >= T) { \
        unsigned slot = atomicAdd(&lcnt, 1u); \
        if (slot < CAND_CAP) \
            sbuf[slot] = (((unsigned long long)(~os_)) << 32) | (unsigned)(idx); \
    } } while (0)
#define E4(v, gb) do { E1((v).x, (gb)); E1((v).y, (gb) + 1); \
                       E1((v).z, (gb) + 2); E1((v).w, (gb) + 3); } while (0)
    if (tid < peel) E1(src[tid], abase + tid);
    for (int i = tid; i < nv; i += 512) {
        const int gb0 = abase + peel + (i << 2);
        if (i + 256 < nv) {
            float4 a0 = s4[i], a1 = s4[i + 256];
            E4(a0, gb0);
            E4(a1, gb0 + 1024);
        } else {
            float4 a0 = s4[i];
            E4(a0, gb0);
        }
    }
    for (int i = tail0 + tid; i < m; i += 256) E1(src[i], abase + i);
#undef E4
#undef E1
    __syncthreads();
    unsigned total = lcnt; if (total > CAND_CAP) total = CAND_CAP;
    if (tid == 0) gbase = atomicAdd(&cnt[bl], total);
    __syncthreads();
    const unsigned gb = gbase;
    for (unsigned i = tid; i < total; i += 256) {
        unsigned g = gb + i;
        if (g < CAND_CAP)
            cand[(size_t)bl * CAND_CAP + g] = sbuf[i];
    }
}

// ---------- K3: per-(b,level) bitonic sort of candidates; keep top-k ----------
__global__ __launch_bounds__(1024) void k_sort(const unsigned long long* __restrict__ cand,
                                               const unsigned* __restrict__ cnt,
                                               unsigned long long* __restrict__ sel) {
    __shared__ unsigned long long keys[CAND_CAP];
    const int bl = blockIdx.x;
    const int b = bl / NLVL, l = bl - (bl / NLVL) * NLVL;
    const int tid = threadIdx.x;     // 1024
    int m = (int)cnt[bl];
    if (m > CAND_CAP) m = CAND_CAP;
    for (int i = tid; i < CAND_CAP; i += 1024)
        keys[i] = (i < m) ? cand[(size_t)bl * CAND_CAP + i] : ~0ULL;
    __syncthreads();
    for (int k = 2; k <= CAND_CAP; k <<= 1) {
        for (int j = k >> 1; j > 0; j >>= 1) {
            int i = ((tid / j) * (j << 1)) + (tid % j);
            int p = i + j;
            bool up = ((i & k) == 0);
            unsigned long long a = keys[i], c = keys[p];
            if ((a > c) == up) { keys[i] = c; keys[p] = a; }
            __syncthreads();
        }
    }
    int kl = lvl_k(l);
    for (int q = tid; q < kl; q += 1024)
        sel[(size_t)b * NSEL + l * 1000 + q] = keys[q];
}

// ---------- binary search in LDS: #elements < key ----------
__device__ __forceinline__ int lbound_lds(const unsigned long long* s, int len,
                                          unsigned long long key) {
    int lo = 0, hi = len;
    while (lo < hi) {
        int mid = (lo + hi) >> 1;
        if (s[mid] < key) lo = mid + 1; else hi = mid;
    }
    return lo;
}

// ---------- K4: decode+clip+valid; global rank via LDS 5-way merge-rank ----------
__global__ void k_decode(const float* __restrict__ deltas, const float* __restrict__ anchors,
                         const unsigned long long* __restrict__ sel,
                         float* __restrict__ boxes_r, float* __restrict__ score_r,
                         float* __restrict__ boxes_l, int* __restrict__ valid_l,
                         int* __restrict__ rankmap, unsigned* __restrict__ boxmax5) {
    __shared__ unsigned long long skey[NSEL];     // 37,928 B
    __shared__ float wmax[16];
    const int b = blockIdx.y;
    const int tid = threadIdx.x;                  // 1024
    for (int i = tid; i < NSEL; i += 1024)
        skey[i] = sel[(size_t)b * NSEL + i];
    __syncthreads();

    int p = blockIdx.x * 1024 + tid;
    bool on = p < NSEL;
    float mx = 0.0f;
    if (on) {
        int l = p / 1000;           // p in [4000,4741) -> 4
        int q = p - l * 1000;
        unsigned long long key = skey[p];
        unsigned a = (unsigned)(key & 0xFFFFFFFFu);
        unsigned os = ~((unsigned)(key >> 32));
        if (a >= A_TOTAL) a = 0;    // impossible-path safety (MAX padding)
        float score = unflipf(os);
        int r = q;
        for (int l2 = 0; l2 < NLVL; ++l2) {
            if (l2 == l) continue;
            r += lbound_lds(skey + l2 * 1000, lvl_k(l2), key);
        }
        const float* dv = deltas + ((size_t)b * A_TOTAL + a) * 4;
        const float* av = anchors + (size_t)a * 4;
        float ax1 = av[0], ay1 = av[1], ax2 = av[2], ay2 = av[3];
        float wa = ax2 - ax1, ha = ay2 - ay1;
        float cxa = ax1 + 0.5f * wa, cya = ay1 + 0.5f * ha;
        float dx = dv[0], dy = dv[1];
        float dw = fminf(dv[2], BBOX_CLIP), dh = fminf(dv[3], BBOX_CLIP);
        float cx = dx * wa + cxa, cy = dy * ha + cya;
        float w = expf(dw) * wa, h = expf(dh) * ha;
        float x1 = cx - 0.5f * w, y1 = cy - 0.5f * h;
        float x2 = cx + 0.5f * w, y2 = cy + 0.5f * h;
        float x1c = fminf(fmaxf(x1, 0.0f), W_IMGF);
        float y1c = fminf(fmaxf(y1, 0.0f), H_IMGF);
        float x2c = fminf(fmaxf(x2, 0.0f), W_IMGF);
        float y2c = fminf(fmaxf(y2, 0.0f), H_IMGF);
        int valid = ((x2c - x1c) >= MIN_SZ) && ((y2c - y1c) >= MIN_SZ);
        mx = fmaxf(fmaxf(x1c, y1c), fmaxf(x2c, y2c));
        size_t rp = (size_t)b * NSEL + r;
        boxes_r[rp * 4 + 0] = x1c; boxes_r[rp * 4 + 1] = y1c;
        boxes_r[rp * 4 + 2] = x2c; boxes_r[rp * 4 + 3] = y2c;
        score_r[rp] = score;
        size_t pp = (size_t)b * NSEL + p;
        boxes_l[pp * 4 + 0] = x1c; boxes_l[pp * 4 + 1] = y1c;
        boxes_l[pp * 4 + 2] = x2c; boxes_l[pp * 4 + 3] = y2c;
        valid_l[pp] = valid;
        rankmap[pp] = r;
    }
    #pragma unroll
    for (int o = 32; o > 0; o >>= 1)
        mx = fmaxf(mx, __shfl_xor(mx, o));
    if ((tid & 63) == 0) wmax[tid >> 6] = mx;
    __syncthreads();
    if (tid == 0) {
        float m2 = wmax[0];
        #pragma unroll
        for (int i = 1; i < 16; ++i) m2 = fmaxf(m2, wmax[i]);
        boxmax5[b * 5 + blockIdx.x] = __float_as_uint(m2);
    }
}

// ---------- K5: suppression bitmask (per (b,level), offset-box IoU) ----------
__global__ void k_mask(const float* __restrict__ boxes_l, const unsigned* __restrict__ boxmax5,
                       unsigned long long* __restrict__ mask) {
    int bl = blockIdx.z;
    int b = bl / NLVL, l = bl - b * NLVL;
    int kl = lvl_k(l);
    int w = blockIdx.x, rg = blockIdx.y, tid = threadIdx.x;
    if (rg * 256 >= kl) return;
    float M = __uint_as_float(boxmax5[b * 5 + 0]);
    #pragma unroll
    for (int j = 1; j < 5; ++j) M = fmaxf(M, __uint_as_float(boxmax5[b * 5 + j]));
    M += 1.0f;
    float off = (float)l * M;
    __shared__ float cb[64][5];
    int j0 = w * 64;
    if (tid < 64) {
        int j = j0 + tid;
        if (j < kl) {
            const float* bp = boxes_l + ((size_t)b * NSEL + l * 1000 + j) * 4;
            float x1 = bp[0] + off, y1 = bp[1] + off, x2 = bp[2] + off, y2 = bp[3] + off;
            cb[tid][0] = x1; cb[tid][1] = y1; cb[tid][2] = x2; cb[tid][3] = y2;
            cb[tid][4] = (x2 - x1) * (y2 - y1);
        }
    }
    __syncthreads();
    int i = rg * 256 + tid;
    if (i >= kl) return;
    unsigned long long word = 0;
    if (j0 + 63 > i) {
        const float* bp = boxes_l + ((size_t)b * NSEL + l * 1000 + i) * 4;
        float ix1 = bp[0] + off, iy1 = bp[1] + off, ix2 = bp[2] + off, iy2 = bp[3] + off;
        float ai = (ix2 - ix1) * (iy2 - iy1);
        int jmax = min(64, kl - j0);
        for (int bb = 0; bb < jmax; ++bb) {
            int jj = j0 + bb;
            if (jj <= i) continue;
            float ltx = fmaxf(ix1, cb[bb][0]), lty = fmaxf(iy1, cb[bb][1]);
            float rbx = fminf(ix2, cb[bb][2]), rby = fminf(iy2, cb[bb][3]);
            float ww = fmaxf(rbx - ltx, 0.0f), hh = fmaxf(rby - lty, 0.0f);
            float inter = ww * hh;
            float iou = inter / ((ai + cb[bb][4]) - inter);   // NaN>th == false, matches jnp
            if (iou > NMS_TH) word |= (1ULL << bb);
        }
    }
    mask[((size_t)bl * 1024 + i) * 16 + w] = word;
}

// ---------- K6: fused resolve (waves 0..4, direct-L2 mask reads) + output ----------
// One block per image. Wave l runs the R3-verified greedy resolve for level l,
// reading the mask straight from global (L2-resident, just written); keep bits
// land in an LDS rank-indexed array; one barrier; then the k_output phase.
__global__ __launch_bounds__(1024) void k_ro(const int* __restrict__ valid_l,
                                             const int* __restrict__ rankmap,
                                             const unsigned long long* __restrict__ mask,
                                             const float* __restrict__ boxes_r,
                                             const float* __restrict__ score_r,
                                             float* __restrict__ out) {
    __shared__ int krank[NSEL];      // 18,964 B (keep bit per global rank)
    __shared__ int ps[1024];
    const int b = blockIdx.x;
    const int tid = threadIdx.x;     // 1024
    const int lane = tid & 63;
    const int wave = tid >> 6;

    if (wave < NLVL) {
        const int l = wave;
        const int kl = lvl_k(l);
        const int bl = b * NLVL + l;
        const int base = b * NSEL + l * 1000;
        unsigned long long keep_w = 0;
        for (int c = 0; c < 16; ++c) {
            int q = c * 64 + lane;
            int vv = (q < kl) ? valid_l[base + q] : 0;
            unsigned long long bm = __ballot(vv);
            if (lane == c) keep_w = bm;
        }
        const int nch = (kl + 63) >> 6;   // 16 or 12
        const unsigned long long* mb = mask + (size_t)bl * 1024 * 16;
        for (int c = 0; c < nch; ++c) {
            unsigned long long kw = __shfl(keep_w, c);   // uniform in wave
            if (kw) {
                const unsigned long long* mrow = mb + (size_t)c * 64 * 16;
                // diagonal word (word c of row c*64+lane)
                unsigned long long diag = mrow[lane * 16 + c];
                unsigned dlo = (unsigned)diag, dhi = (unsigned)(diag >> 32);
                unsigned long long nz = __ballot(diag != 0ULL);
                unsigned long long rem = kw & nz;
                while (rem) {
                    int rr = __ffsll((long long)rem) - 1;
                    unsigned lo = __builtin_amdgcn_readlane(dlo, rr);
                    unsigned hi = __builtin_amdgcn_readlane(dhi, rr);
                    unsigned long long d = ((unsigned long long)hi << 32) | lo;
                    kw &= ~d;
                    rem &= ~(d | (1ULL << rr));
                }
                // batched cross-chunk suppression: lane w<16 ORs word w of kept rows
                unsigned long long supp = 0;
                if (lane < 16) {
                    #pragma unroll
                    for (int rr = 0; rr < 64; ++rr) {
                        unsigned long long m = mrow[rr * 16 + lane];
                        supp |= (((kw >> rr) & 1ULL) ? m : 0ULL);
                    }
                }
                if (lane == c) keep_w = kw;
                else if (lane < 16 && lane > c) keep_w &= ~supp;
            }
        }
        // scatter keep bits to LDS in global-rank order (ranks are a
        // permutation of [0,NSEL) across the 5 waves -> full coverage)
        for (int c = 0; c < 16; ++c) {
            unsigned long long kwc = __shfl(keep_w, c);
            int q = c * 64 + lane;
            if (q < kl)
                krank[rankmap[base + q]] = (int)((kwc >> lane) & 1ULL);
        }
    }
    __syncthreads();

    // ---- output phase (k_output logic, keep flags from LDS) ----
    float* ob = out + (size_t)b * POST_NMS * 4;
    float* osc = out + (size_t)B_IMGS * POST_NMS * 4 + (size_t)b * POST_NMS;
    for (int p = tid; p < POST_NMS; p += 1024) {
        ob[p * 4 + 0] = 0.0f; ob[p * 4 + 1] = 0.0f;
        ob[p * 4 + 2] = 0.0f; ob[p * 4 + 3] = 0.0f;
        osc[p] = NEGV;
    }
    __syncthreads();   // zero-init drained before scatter
    const int CH = 5;  // 5*1024 = 5120 >= 4741
    int basei = tid * CH;
    int c0 = 0;
    #pragma unroll
    for (int k = 0; k < CH; ++k) {
        int rr = basei + k;
        if (rr < NSEL) c0 += krank[rr];
    }
    ps[tid] = c0;
    __syncthreads();
    for (int ofs = 1; ofs < 1024; ofs <<= 1) {
        int v = (tid >= ofs) ? ps[tid - ofs] : 0;
        __syncthreads();
        ps[tid] += v;
        __syncthreads();
    }
    int p = ps[tid] - c0;   // exclusive prefix
    #pragma unroll
    for (int k = 0; k < CH; ++k) {
        int rr = basei + k;
        if (rr < NSEL && krank[rr]) {
            if (p < POST_NMS) {
                const float* bp = boxes_r + ((size_t)b * NSEL + rr) * 4;
                ob[p * 4 + 0] = bp[0]; ob[p * 4 + 1] = bp[1];
                ob[p * 4 + 2] = bp[2]; ob[p * 4 + 3] = bp[3];
                osc[p] = score_r[(size_t)b * NSEL + rr];
            }
            ++p;
        }
    }
}

extern "C" void kernel_launch(void* const* d_in, const int* in_sizes, int n_in,
                              void* d_out, int out_size, void* d_ws, size_t ws_size,
                              hipStream_t stream) {
    const float* obj     = (const float*)d_in[0];   // [4, 242991]
    const float* deltas  = (const float*)d_in[1];   // [4, 242991, 4]
    const float* anchors = (const float*)d_in[2];   // [242991, 4]
    float* out = (float*)d_out;                     // [4,1000,4] ++ [4,1000]

    char* ws = (char*)d_ws;
    unsigned*            boxmax5 = (unsigned*)(ws + OFF_BM5);
    unsigned*            cnt     = (unsigned*)(ws + OFF_CNT);
    unsigned*            hist_sl = (unsigned*)(ws + OFF_HSL);
    unsigned*            part_sl = (unsigned*)(ws + OFF_PSL);
    unsigned long long*  cand    = (unsigned long long*)(ws + OFF_CAND);
    unsigned long long*  sel     = (unsigned long long*)(ws + OFF_SEL);
    float*               boxes_r = (float*)(ws + OFF_BOXR);
    float*               score_r = (float*)(ws + OFF_SCR);
    float*               boxes_l = (float*)(ws + OFF_BOXL);
    int*                 valid_l = (int*)(ws + OFF_VAL);
    int*                 rankmap = (int*)(ws + OFF_RMAP);
    unsigned long long*  maskp   = (unsigned long long*)(ws + OFF_MASK);

    (void)in_sizes; (void)n_in; (void)out_size; (void)ws_size; (void)WS_NEED;

    // No memset: hist/part slices are plain-store overwritten; cnt is zeroed
    // by k_hist's l4 block (visible to k_compact at the kernel boundary);
    // boxmax5 is plain-stored by k_decode; krank/keep lives in LDS.
    k_hist<<<B_IMGS * HBLK_PER_IMG, 512, 0, stream>>>(obj, hist_sl, part_sl, cnt);
    k_compact<<<B_IMGS * CBLK_PER_IMG, 256, 0, stream>>>(obj, hist_sl, part_sl, cnt, cand);
    k_sort<<<NBL, 1024, 0, stream>>>(cand, cnt, sel);
    k_decode<<<dim3(5, B_IMGS), 1024, 0, stream>>>(
        deltas, anchors, sel, boxes_r, score_r, boxes_l, valid_l, rankmap, boxmax5);
    k_mask<<<dim3(16, 4, NBL), 256, 0, stream>>>(boxes_l, boxmax5, maskp);
    k_ro<<<B_IMGS, 1024, 0, stream>>>(valid_l, rankmap, maskp, boxes_r, score_r, out);
}

// Round 7
// 176.407 us; speedup vs baseline: 1.4258x; 1.0484x over previous
//
#include <hip/hip_runtime.h>
#include <stdint.h>

// Disable FMA contraction file-wide: we must replicate the reference's
// per-op f32 rounding (decode + IoU) to avoid NMS decision flips.
#pragma clang fp contract(off)

#define B_IMGS   4
#define NLVL     5
#define A_TOTAL  242991
#define NSEL     4741          // 1000*4 + 741
#define NBUCK    8192          // 13-bit buckets: sign+exp+4 mantissa (os>>19)
#define BSHIFT   19
#define CAND_CAP 2048
#define POST_NMS 1000
#define NBL      (B_IMGS * NLVL)
#define NMS_TH   0.7f
#define NEGV     (-1e10f)
#define W_IMGF   1216.0f
#define H_IMGF   800.0f
#define MIN_SZ   1e-3f
#define BBOX_CLIP 4.135166556742356f   // log(1000/16), rounded to f32 by compiler

#define NSLICE_PER_IMG 34      // hist slices per image (l0:24 l1:6 l2:2 l3:1 l4:1-unused)

// ---------- level helpers ----------
__device__ __forceinline__ int lvl_k(int l) { return (l == 4) ? 741 : 1000; }

// ---------- order-preserving float<->uint ----------
__device__ __forceinline__ unsigned flipf(float f) {
    unsigned u = __float_as_uint(f);
    return u ^ (unsigned)(((int)u >> 31) | 0x80000000);
}
__device__ __forceinline__ float unflipf(unsigned os) {
    unsigned u = (os & 0x80000000u) ? (os ^ 0x80000000u) : ~os;
    return __uint_as_float(u);
}

// ---------- async global->LDS DMA (16B per lane, wave-uniform LDS base) ----------
__device__ __forceinline__ void async_cp16(const void* g, void* l) {
    __builtin_amdgcn_global_load_lds(
        (const __attribute__((address_space(1))) unsigned*)g,
        (__attribute__((address_space(3))) unsigned*)l,
        16, 0, 0);
}

// ---------- workspace layout (NOTHING pre-zeroed; cnt zeroed by k_hist) ----------
static constexpr size_t OFF_BM5   = 0;                                        // u32[20]
static constexpr size_t OFF_CNT   = 128;                                      // u32[20]
static constexpr size_t OFF_HSL   = 256;                                      // u32[4*34*8192]
static constexpr size_t OFF_PSL   = OFF_HSL  + (size_t)B_IMGS * NSLICE_PER_IMG * NBUCK * 4;
static constexpr size_t OFF_CAND  = OFF_PSL  + (size_t)B_IMGS * NSLICE_PER_IMG * 256 * 4;
static constexpr size_t OFF_SEL   = OFF_CAND + (size_t)NBL * CAND_CAP * 8;
static constexpr size_t OFF_BOXR  = OFF_SEL  + (size_t)B_IMGS * NSEL * 8;
static constexpr size_t OFF_SCR   = OFF_BOXR + (size_t)B_IMGS * NSEL * 16;
static constexpr size_t OFF_BOXL  = OFF_SCR  + (size_t)B_IMGS * NSEL * 4;
static constexpr size_t OFF_VAL   = OFF_BOXL + (size_t)B_IMGS * NSEL * 16;
static constexpr size_t OFF_RMAP  = OFF_VAL  + (size_t)B_IMGS * NSEL * 4;
static constexpr size_t OFF_KEEP  = OFF_RMAP + (size_t)B_IMGS * NSEL * 4;
static constexpr size_t OFF_MASK  = (OFF_KEEP + (size_t)B_IMGS * NSEL * 4 + 15) & ~(size_t)15;
static constexpr size_t WS_NEED   = OFF_MASK + (size_t)NBL * 1024 * 16 * 8;   // ~8.5 MB

// ---------- K1: per-span LDS histogram -> private global slice (no atomics) ----------
// 34 blocks/image, 512 threads. Slice s of image b at hist_sl[(b*34+s)*8192];
// per-slice chunk sums at part_sl[(b*34+s)*256]. l4 block zeroes cnt instead
// (n<=k: compact uses T=0, no hist needed).
#define HBLK_PER_IMG 34
__global__ __launch_bounds__(512) void k_hist(const float* __restrict__ obj,
                                              unsigned* __restrict__ hist_sl,
                                              unsigned* __restrict__ part_sl,
                                              unsigned* __restrict__ cnt) {
    __shared__ __align__(16) unsigned lh[NBUCK];   // 32 KB
    const int tid = threadIdx.x;     // 512
    const int b = blockIdx.x / HBLK_PER_IMG;
    const int r = blockIdx.x - b * HBLK_PER_IMG;
    if (r == 33) {                   // l4 block: just zero cnt once (b==0)
        if (b == 0 && tid < NBL) cnt[tid] = 0;
        return;
    }
    int sofs, sub, chunk, lstart, n;
    if (r < 24)      { sofs = 0;  sub = r;      chunk = 7600; lstart = 0;      n = 182400; }
    else if (r < 30) { sofs = 24; sub = r - 24; chunk = 7600; lstart = 182400; n = 45600; }
    else if (r < 32) { sofs = 30; sub = r - 30; chunk = 5700; lstart = 228000; n = 11400; }
    else             { sofs = 32; sub = 0;      chunk = 2850; lstart = 239400; n = 2850; }
    #pragma unroll
    for (int i = tid; i < NBUCK; i += 512) lh[i] = 0;
    __syncthreads();
    const int s0 = sub * chunk;
    const int m = min(chunk, n - s0);
    const float* src = obj + (size_t)b * A_TOTAL + lstart + s0;
    // vectorized histogram (float4 + 4-deep unroll; peel to 16B alignment)
    const int peel0 = (int)(((16u - ((unsigned)(uintptr_t)src & 15u)) & 15u) >> 2);
    const int peel  = (peel0 < m) ? peel0 : m;
    const int nv    = (m - peel) >> 2;
    const float4* s4 = (const float4*)(src + peel);
    const int tail0 = peel + (nv << 2);
#define H1(f) atomicAdd(&lh[flipf(f) >> BSHIFT], 1u)
#define H4(v) do { H1((v).x); H1((v).y); H1((v).z); H1((v).w); } while (0)
    if (tid < peel) H1(src[tid]);
    for (int i = tid; i < nv; i += 2048) {
        if (i + 1536 < nv) {
            float4 a0 = s4[i], a1 = s4[i + 512], a2 = s4[i + 1024], a3 = s4[i + 1536];
            H4(a0); H4(a1); H4(a2); H4(a3);
        } else {
            float4 a0 = s4[i]; H4(a0);
            if (i + 512  < nv) { float4 a = s4[i + 512];  H4(a); }
            if (i + 1024 < nv) { float4 a = s4[i + 1024]; H4(a); }
        }
    }
    for (int i = tail0 + tid; i < m; i += 512) H1(src[i]);
#undef H4
#undef H1
    __syncthreads();
    const int slice = b * NSLICE_PER_IMG + sofs + sub;
    unsigned* gh = hist_sl + (size_t)slice * NBUCK;
    #pragma unroll
    for (int i = tid; i < NBUCK / 4; i += 512)
        ((uint4*)gh)[i] = ((const uint4*)lh)[i];
    if (tid < 256) {
        unsigned s = 0;
        #pragma unroll
        for (int i = 0; i < 32; ++i) s += lh[tid * 32 + ((i + tid) & 31)];
        part_sl[(size_t)slice * 256 + tid] = s;
    }
}

// ---------- K2: threshold (from slice sums) + vectorized compact ----------
// 65 blocks/image, 256 threads. Threshold logic identical to R3-verified
// wave scan; inputs are integer sums over this bl's slices (deterministic,
// identical in every block of the bl).
#define CBLK_PER_IMG 65
__global__ __launch_bounds__(256) void k_compact(const float* __restrict__ obj,
                                                 const unsigned* __restrict__ hist_sl,
                                                 const unsigned* __restrict__ part_sl,
                                                 unsigned* __restrict__ cnt,
                                                 unsigned long long* __restrict__ cand) {
    __shared__ unsigned long long sbuf[CAND_CAP];   // 16 KB staging
    __shared__ unsigned wsum[4];
    __shared__ unsigned fcnt[4];
    __shared__ unsigned s_cum, s_thr, lcnt, gbase;
    const int tid = threadIdx.x;     // 256
    const int b = blockIdx.x / CBLK_PER_IMG;
    const int r = blockIdx.x - b * CBLK_PER_IMG;
    int l, sofs, nsub, sub, chunk, lstart, n;
    if (r < 48)      { l = 0; sofs = 0;  nsub = 24; sub = r;      chunk = 3800; lstart = 0;      n = 182400; }
    else if (r < 60) { l = 1; sofs = 24; nsub = 6;  sub = r - 48; chunk = 3800; lstart = 182400; n = 45600; }
    else if (r < 63) { l = 2; sofs = 30; nsub = 2;  sub = r - 60; chunk = 3800; lstart = 228000; n = 11400; }
    else if (r == 63){ l = 3; sofs = 32; nsub = 1;  sub = 0;      chunk = 2850; lstart = 239400; n = 2850; }
    else             { l = 4; sofs = 33; nsub = 0;  sub = 0;      chunk = 741;  lstart = 242250; n = 741; }
    const int bl = b * NLVL + l;
    const int kl = lvl_k(l);
    if (tid == 0) { lcnt = 0; s_cum = 0; }
    __syncthreads();
    unsigned T = 0;
    if (l < 4) {   // l4: n <= k -> every element passes, T = 0
        const int lane = tid & 63, wv = tid >> 6;
        // stage 1: suffix(t) over 256 chunk-sums (t = 255 - tid)
        const unsigned* pb = part_sl + (size_t)(b * NSLICE_PER_IMG + sofs) * 256 + (255 - tid);
        unsigned x = 0;
        #pragma unroll 6
        for (int s = 0; s < nsub; ++s) x += pb[(size_t)s * 256];
        #pragma unroll
        for (int d = 1; d < 64; d <<= 1) {
            unsigned up = __shfl_up(x, d);
            if (lane >= d) x += up;
        }
        if (lane == 63) wsum[wv] = x;
        __syncthreads();
        unsigned add = 0;
        #pragma unroll
        for (int u = 0; u < 3; ++u) if (u < wv) add += wsum[u];
        const unsigned suffix = x + add;                 // suffix(255 - tid)
        unsigned long long bm = __ballot(suffix >= (unsigned)kl);
        if (lane == 0) fcnt[wv] = (unsigned)__popcll(bm);
        __syncthreads();
        const int chnk = (int)(fcnt[0] + fcnt[1] + fcnt[2] + fcnt[3]) - 1;
        if ((255 - tid) == chnk + 1) s_cum = suffix;     // 0 if chnk==255
        __syncthreads();
        // stage 2 (wave 0): largest bucket in chunk with suffix >= kl
        if (tid < 64) {
            unsigned y = 0;
            if (tid < 32) {
                const unsigned* hb = hist_sl + (size_t)(b * NSLICE_PER_IMG + sofs) * NBUCK
                                   + chnk * 32 + (31 - tid);
                #pragma unroll 6
                for (int s = 0; s < nsub; ++s) y += hb[(size_t)s * NBUCK];
            }
            #pragma unroll
            for (int d = 1; d < 32; d <<= 1) {
                unsigned up = __shfl_up(y, d);
                if (tid >= d) y += up;
            }
            unsigned suf2 = s_cum + y;                   // bucket i = 31 - tid
            unsigned long long bm2 = __ballot((tid < 32) && (suf2 >= (unsigned)kl));
            if (tid == 0) {
                int istar = (int)__popcll(bm2) - 1;
                s_thr = (unsigned)(chnk * 32 + istar);
            }
        }
        __syncthreads();
        T = s_thr;
    }
    // ---- vectorized pass filter into LDS staging ----
    const int s0 = sub * chunk;
    const int m = min(chunk, n - s0);
    const int abase = lstart + s0;
    const float* src = obj + (size_t)b * A_TOTAL + abase;
    const int peel0 = (int)(((16u - ((unsigned)(uintptr_t)src & 15u)) & 15u) >> 2);
    const int peel  = (peel0 < m) ? peel0 : m;
    const int nv    = (m - peel) >> 2;
    const float4* s4 = (const float4*)(src + peel);
    const int tail0 = peel + (nv << 2);
#define E1(f, idx) do { unsigned os_ = flipf(f); \
    if ((os_ >> BSHIFT) >= T) { \
        unsigned slot = atomicAdd(&lcnt, 1u); \
        if (slot < CAND_CAP) \
            sbuf[slot] = (((unsigned long long)(~os_)) << 32) | (unsigned)(idx); \
    } } while (0)
#define E4(v, gb) do { E1((v).x, (gb)); E1((v).y, (gb) + 1); \
                       E1((v).z, (gb) + 2); E1((v).w, (gb) + 3); } while (0)
    if (tid < peel) E1(src[tid], abase + tid);
    for (int i = tid; i < nv; i += 512) {
        const int gb0 = abase + peel + (i << 2);
        if (i + 256 < nv) {
            float4 a0 = s4[i], a1 = s4[i + 256];
            E4(a0, gb0);
            E4(a1, gb0 + 1024);
        } else {
            float4 a0 = s4[i];
            E4(a0, gb0);
        }
    }
    for (int i = tail0 + tid; i < m; i += 256) E1(src[i], abase + i);
#undef E4
#undef E1
    __syncthreads();
    unsigned total = lcnt; if (total > CAND_CAP) total = CAND_CAP;
    if (tid == 0) gbase = atomicAdd(&cnt[bl], total);
    __syncthreads();
    const unsigned gb = gbase;
    for (unsigned i = tid; i < total; i += 256) {
        unsigned g = gb + i;
        if (g < CAND_CAP)
            cand[(size_t)bl * CAND_CAP + g] = sbuf[i];
    }
}

// ---------- K3: per-(b,level) bitonic sort of candidates; keep top-k ----------
__global__ __launch_bounds__(1024) void k_sort(const unsigned long long* __restrict__ cand,
                                               const unsigned* __restrict__ cnt,
                                               unsigned long long* __restrict__ sel) {
    __shared__ unsigned long long keys[CAND_CAP];
    const int bl = blockIdx.x;
    const int b = bl / NLVL, l = bl - (bl / NLVL) * NLVL;
    const int tid = threadIdx.x;     // 1024
    int m = (int)cnt[bl];
    if (m > CAND_CAP) m = CAND_CAP;
    for (int i = tid; i < CAND_CAP; i += 1024)
        keys[i] = (i < m) ? cand[(size_t)bl * CAND_CAP + i] : ~0ULL;
    __syncthreads();
    for (int k = 2; k <= CAND_CAP; k <<= 1) {
        for (int j = k >> 1; j > 0; j >>= 1) {
            int i = ((tid / j) * (j << 1)) + (tid % j);
            int p = i + j;
            bool up = ((i & k) == 0);
            unsigned long long a = keys[i], c = keys[p];
            if ((a > c) == up) { keys[i] = c; keys[p] = a; }
            __syncthreads();
        }
    }
    int kl = lvl_k(l);
    for (int q = tid; q < kl; q += 1024)
        sel[(size_t)b * NSEL + l * 1000 + q] = keys[q];
}

// ---------- binary search in LDS: #elements < key ----------
__device__ __forceinline__ int lbound_lds(const unsigned long long* s, int len,
                                          unsigned long long key) {
    int lo = 0, hi = len;
    while (lo < hi) {
        int mid = (lo + hi) >> 1;
        if (s[mid] < key) lo = mid + 1; else hi = mid;
    }
    return lo;
}

// ---------- K4: decode+clip+valid; global rank via LDS 5-way merge-rank ----------
__global__ void k_decode(const float* __restrict__ deltas, const float* __restrict__ anchors,
                         const unsigned long long* __restrict__ sel,
                         float* __restrict__ boxes_r, float* __restrict__ score_r,
                         float* __restrict__ boxes_l, int* __restrict__ valid_l,
                         int* __restrict__ rankmap, unsigned* __restrict__ boxmax5) {
    __shared__ unsigned long long skey[NSEL];     // 37,928 B
    __shared__ float wmax[16];
    const int b = blockIdx.y;
    const int tid = threadIdx.x;                  // 1024
    for (int i = tid; i < NSEL; i += 1024)
        skey[i] = sel[(size_t)b * NSEL + i];
    __syncthreads();

    int p = blockIdx.x * 1024 + tid;
    bool on = p < NSEL;
    float mx = 0.0f;
    if (on) {
        int l = p / 1000;           // p in [4000,4741) -> 4
        int q = p - l * 1000;
        unsigned long long key = skey[p];
        unsigned a = (unsigned)(key & 0xFFFFFFFFu);
        unsigned os = ~((unsigned)(key >> 32));
        if (a >= A_TOTAL) a = 0;    // impossible-path safety (MAX padding)
        float score = unflipf(os);
        int r = q;
        for (int l2 = 0; l2 < NLVL; ++l2) {
            if (l2 == l) continue;
            r += lbound_lds(skey + l2 * 1000, lvl_k(l2), key);
        }
        const float* dv = deltas + ((size_t)b * A_TOTAL + a) * 4;
        const float* av = anchors + (size_t)a * 4;
        float ax1 = av[0], ay1 = av[1], ax2 = av[2], ay2 = av[3];
        float wa = ax2 - ax1, ha = ay2 - ay1;
        float cxa = ax1 + 0.5f * wa, cya = ay1 + 0.5f * ha;
        float dx = dv[0], dy = dv[1];
        float dw = fminf(dv[2], BBOX_CLIP), dh = fminf(dv[3], BBOX_CLIP);
        float cx = dx * wa + cxa, cy = dy * ha + cya;
        float w = expf(dw) * wa, h = expf(dh) * ha;
        float x1 = cx - 0.5f * w, y1 = cy - 0.5f * h;
        float x2 = cx + 0.5f * w, y2 = cy + 0.5f * h;
        float x1c = fminf(fmaxf(x1, 0.0f), W_IMGF);
        float y1c = fminf(fmaxf(y1, 0.0f), H_IMGF);
        float x2c = fminf(fmaxf(x2, 0.0f), W_IMGF);
        float y2c = fminf(fmaxf(y2, 0.0f), H_IMGF);
        int valid = ((x2c - x1c) >= MIN_SZ) && ((y2c - y1c) >= MIN_SZ);
        mx = fmaxf(fmaxf(x1c, y1c), fmaxf(x2c, y2c));
        size_t rp = (size_t)b * NSEL + r;
        boxes_r[rp * 4 + 0] = x1c; boxes_r[rp * 4 + 1] = y1c;
        boxes_r[rp * 4 + 2] = x2c; boxes_r[rp * 4 + 3] = y2c;
        score_r[rp] = score;
        size_t pp = (size_t)b * NSEL + p;
        boxes_l[pp * 4 + 0] = x1c; boxes_l[pp * 4 + 1] = y1c;
        boxes_l[pp * 4 + 2] = x2c; boxes_l[pp * 4 + 3] = y2c;
        valid_l[pp] = valid;
        rankmap[pp] = r;
    }
    #pragma unroll
    for (int o = 32; o > 0; o >>= 1)
        mx = fmaxf(mx, __shfl_xor(mx, o));
    if ((tid & 63) == 0) wmax[tid >> 6] = mx;
    __syncthreads();
    if (tid == 0) {
        float m2 = wmax[0];
        #pragma unroll
        for (int i = 1; i < 16; ++i) m2 = fmaxf(m2, wmax[i]);
        boxmax5[b * 5 + blockIdx.x] = __float_as_uint(m2);
    }
}

// ---------- K5: suppression bitmask (per (b,level), offset-box IoU) ----------
__global__ void k_mask(const float* __restrict__ boxes_l, const unsigned* __restrict__ boxmax5,
                       unsigned long long* __restrict__ mask) {
    int bl = blockIdx.z;
    int b = bl / NLVL, l = bl - b * NLVL;
    int kl = lvl_k(l);
    int w = blockIdx.x, rg = blockIdx.y, tid = threadIdx.x;
    if (rg * 256 >= kl) return;
    float M = __uint_as_float(boxmax5[b * 5 + 0]);
    #pragma unroll
    for (int j = 1; j < 5; ++j) M = fmaxf(M, __uint_as_float(boxmax5[b * 5 + j]));
    M += 1.0f;
    float off = (float)l * M;
    __shared__ float cb[64][5];
    int j0 = w * 64;
    if (tid < 64) {
        int j = j0 + tid;
        if (j < kl) {
            const float* bp = boxes_l + ((size_t)b * NSEL + l * 1000 + j) * 4;
            float x1 = bp[0] + off, y1 = bp[1] + off, x2 = bp[2] + off, y2 = bp[3] + off;
            cb[tid][0] = x1; cb[tid][1] = y1; cb[tid][2] = x2; cb[tid][3] = y2;
            cb[tid][4] = (x2 - x1) * (y2 - y1);
        }
    }
    __syncthreads();
    int i = rg * 256 + tid;
    if (i >= kl) return;
    unsigned long long word = 0;
    if (j0 + 63 > i) {
        const float* bp = boxes_l + ((size_t)b * NSEL + l * 1000 + i) * 4;
        float ix1 = bp[0] + off, iy1 = bp[1] + off, ix2 = bp[2] + off, iy2 = bp[3] + off;
        float ai = (ix2 - ix1) * (iy2 - iy1);
        int jmax = min(64, kl - j0);
        for (int bb = 0; bb < jmax; ++bb) {
            int jj = j0 + bb;
            if (jj <= i) continue;
            float ltx = fmaxf(ix1, cb[bb][0]), lty = fmaxf(iy1, cb[bb][1]);
            float rbx = fminf(ix2, cb[bb][2]), rby = fminf(iy2, cb[bb][3]);
            float ww = fmaxf(rbx - ltx, 0.0f), hh = fmaxf(rby - lty, 0.0f);
            float inter = ww * hh;
            float iou = inter / ((ai + cb[bb][4]) - inter);   // NaN>th == false, matches jnp
            if (iou > NMS_TH) word |= (1ULL << bb);
        }
    }
    mask[((size_t)bl * 1024 + i) * 16 + w] = word;
}

// ---------- K6: sequential greedy resolve (1 wave per (b,level)) ----------
// R3/R5-verified kernel: serial loop visits ONLY rows with nonzero diag word;
// mask chunks DMA'd to LDS via global_load_lds, double-buffered (prefetch of
// chunk c+1 overlaps processing of chunk c — the thing R6's k_ro lost).
__global__ void k_resolve(const int* __restrict__ valid_l, const int* __restrict__ rankmap,
                          const unsigned long long* __restrict__ mask, int* __restrict__ keep_r) {
    const int bl = blockIdx.x;
    const int b = bl / NLVL, l = bl - b * NLVL;
    const int kl = lvl_k(l);
    const int lane = threadIdx.x;     // 64 threads = 1 wave
    __shared__ __align__(16) unsigned long long sbufA[64 * 16];  // 8 KB, mirror layout
    __shared__ __align__(16) unsigned long long sbufB[64 * 16];  // 8 KB
    const int base = b * NSEL + l * 1000;

    // keep word per chunk, distributed: lane w (w<16) holds chunk w's keep bits
    unsigned long long keep_w = 0;
    for (int c = 0; c < 16; ++c) {
        int q = c * 64 + lane;
        int vv = (q < kl) ? valid_l[base + q] : 0;
        unsigned long long bm = __ballot(vv);
        if (lane == c) keep_w = bm;
    }

    const int nch = (kl + 63) >> 6;   // 16 or 12
    const char* mbyte = (const char*)(mask + (size_t)bl * 1024 * 16);

    // DMA chunk 0 -> sbufA (8 x 1KB instructions; lane scatters 16B each)
    {
        const char* g0 = mbyte + (size_t)lane * 16;
        #pragma unroll
        for (int j = 0; j < 8; ++j)
            async_cp16(g0 + j * 1024, (char*)sbufA + j * 1024);
    }

    for (int c = 0; c < nch; ++c) {
        unsigned long long* cur = (c & 1) ? sbufB : sbufA;
        unsigned long long* nxt = (c & 1) ? sbufA : sbufB;
        __syncthreads();                       // drains vmcnt: chunk c staged
        if (c + 1 < nch) {
            const char* g1 = mbyte + (size_t)(c + 1) * 8192 + (size_t)lane * 16;
            #pragma unroll
            for (int j = 0; j < 8; ++j)
                async_cp16(g1 + j * 1024, (char*)nxt + j * 1024);
        }
        unsigned long long kw = __shfl(keep_w, c);   // uniform
        if (kw) {
            // diagonal word (word c of this lane's row)
            unsigned long long diag = cur[lane * 16 + c];
            unsigned dlo = (unsigned)diag, dhi = (unsigned)(diag >> 32);
            // rows with zero diag suppress nothing in-chunk: skip them wholesale
            unsigned long long nz = __ballot(diag != 0ULL);
            unsigned long long rem = kw & nz;
            while (rem) {
                int r = __ffsll((long long)rem) - 1;
                unsigned lo = __builtin_amdgcn_readlane(dlo, r);
                unsigned hi = __builtin_amdgcn_readlane(dhi, r);
                unsigned long long d = ((unsigned long long)hi << 32) | lo;
                kw &= ~d;
                rem &= ~(d | (1ULL << r));
            }
            // batched cross-chunk suppression: lane w<16 ORs word w of kept rows
            unsigned long long supp = 0;
            if (lane < 16) {
                #pragma unroll
                for (int r = 0; r < 64; ++r) {
                    unsigned long long m = cur[r * 16 + lane];
                    supp |= (((kw >> r) & 1ULL) ? m : 0ULL);
                }
            }
            if (lane == c) keep_w = kw;
            else if (lane < 16 && lane > c) keep_w &= ~supp;
        }
    }
    __syncthreads();
    // scatter keep bits to global-rank order
    for (int c = 0; c < 16; ++c) {
        unsigned long long kwc = __shfl(keep_w, c);
        int q = c * 64 + lane;
        if (q < kl)
            keep_r[b * NSEL + rankmap[base + q]] = (int)((kwc >> lane) & 1ULL);
    }
}

// ---------- K7: compact kept entries (score order) into output ----------
__global__ void k_output(const int* __restrict__ keep_r, const float* __restrict__ boxes_r,
                         const float* __restrict__ score_r, float* __restrict__ out) {
    int b = blockIdx.x, tid = threadIdx.x;    // 1024
    float* ob = out + (size_t)b * POST_NMS * 4;
    float* osc = out + (size_t)B_IMGS * POST_NMS * 4 + (size_t)b * POST_NMS;
    for (int p = tid; p < POST_NMS; p += 1024) {
        ob[p * 4 + 0] = 0.0f; ob[p * 4 + 1] = 0.0f;
        ob[p * 4 + 2] = 0.0f; ob[p * 4 + 3] = 0.0f;
        osc[p] = NEGV;
    }
    __syncthreads();   // global writes drained before barrier (vmcnt)
    const int CH = 5;  // 5*1024 = 5120 >= 4741
    int base = tid * CH;
    int cnt = 0;
    #pragma unroll
    for (int k = 0; k < CH; ++k) {
        int r = base + k;
        if (r < NSEL) cnt += keep_r[b * NSEL + r];
    }
    __shared__ int ps[1024];
    ps[tid] = cnt;
    __syncthreads();
    for (int ofs = 1; ofs < 1024; ofs <<= 1) {
        int v = (tid >= ofs) ? ps[tid - ofs] : 0;
        __syncthreads();
        ps[tid] += v;
        __syncthreads();
    }
    int p = ps[tid] - cnt;   // exclusive prefix
    #pragma unroll
    for (int k = 0; k < CH; ++k) {
        int r = base + k;
        if (r < NSEL && keep_r[b * NSEL + r]) {
            if (p < POST_NMS) {
                const float* bp = boxes_r + ((size_t)b * NSEL + r) * 4;
                ob[p * 4 + 0] = bp[0]; ob[p * 4 + 1] = bp[1];
                ob[p * 4 + 2] = bp[2]; ob[p * 4 + 3] = bp[3];
                osc[p] = score_r[(size_t)b * NSEL + r];
            }
            ++p;
        }
    }
}

extern "C" void kernel_launch(void* const* d_in, const int* in_sizes, int n_in,
                              void* d_out, int out_size, void* d_ws, size_t ws_size,
                              hipStream_t stream) {
    const float* obj     = (const float*)d_in[0];   // [4, 242991]
    const float* deltas  = (const float*)d_in[1];   // [4, 242991, 4]
    const float* anchors = (const float*)d_in[2];   // [242991, 4]
    float* out = (float*)d_out;                     // [4,1000,4] ++ [4,1000]

    char* ws = (char*)d_ws;
    unsigned*            boxmax5 = (unsigned*)(ws + OFF_BM5);
    unsigned*            cnt     = (unsigned*)(ws + OFF_CNT);
    unsigned*            hist_sl = (unsigned*)(ws + OFF_HSL);
    unsigned*            part_sl = (unsigned*)(ws + OFF_PSL);
    unsigned long long*  cand    = (unsigned long long*)(ws + OFF_CAND);
    unsigned long long*  sel     = (unsigned long long*)(ws + OFF_SEL);
    float*               boxes_r = (float*)(ws + OFF_BOXR);
    float*               score_r = (float*)(ws + OFF_SCR);
    float*               boxes_l = (float*)(ws + OFF_BOXL);
    int*                 valid_l = (int*)(ws + OFF_VAL);
    int*                 rankmap = (int*)(ws + OFF_RMAP);
    int*                 keep_r  = (int*)(ws + OFF_KEEP);
    unsigned long long*  maskp   = (unsigned long long*)(ws + OFF_MASK);

    (void)in_sizes; (void)n_in; (void)out_size; (void)ws_size; (void)WS_NEED;

    // No memset: hist/part slices are plain-store overwritten; cnt is zeroed
    // by k_hist's l4 block (visible to k_compact at the kernel boundary);
    // boxmax5 plain-stored by k_decode; keep_r fully written by k_resolve.
    k_hist<<<B_IMGS * HBLK_PER_IMG, 512, 0, stream>>>(obj, hist_sl, part_sl, cnt);
    k_compact<<<B_IMGS * CBLK_PER_IMG, 256, 0, stream>>>(obj, hist_sl, part_sl, cnt, cand);
    k_sort<<<NBL, 1024, 0, stream>>>(cand, cnt, sel);
    k_decode<<<dim3(5, B_IMGS), 1024, 0, stream>>>(
        deltas, anchors, sel, boxes_r, score_r, boxes_l, valid_l, rankmap, boxmax5);
    k_mask<<<dim3(16, 4, NBL), 256, 0, stream>>>(boxes_l, boxmax5, maskp);
    k_resolve<<<NBL, 64, 0, stream>>>(valid_l, rankmap, maskp, keep_r);
    k_output<<<B_IMGS, 1024, 0, stream>>>(keep_r, boxes_r, score_r, out);
}